// Round 13
// baseline (526.540 us; speedup 1.0000x reference)
//
#include <hip/hip_runtime.h>
#include <hip/hip_bf16.h>
#include <hip/hip_fp8.h>
#include <stdint.h>

#define N_NODES 50000
#define N_EDGES 800000
#define NFEAT 512
#define NHID 512
#define NCLASS 128
#define MPAD 50048   // 391 * 128

#define HIST_BLOCKS 64       // LDS-range histogram blocks
#define NODES_PER_HB 784     // 64 * 784 = 50176 >= 50000
#define CONVX_BLOCKS 12512   // MPAD*512/8/256
#define CONVW1_BLOCKS 128    // 512*512/8/256
#define CONVW2_BLOCKS 32     // 128*512/8/256
#define G1_BM 391
#define G1_BLOCKS 1564       // 391*4
#define FILL_BLOCKS 3125

typedef short short8 __attribute__((ext_vector_type(8)));
typedef float f32x4 __attribute__((ext_vector_type(4)));
typedef float f32x2 __attribute__((ext_vector_type(2)));

__device__ __forceinline__ ushort f2bf(float f) {
  union { float f; uint32_t u; } v; v.f = f;
  uint32_t u = v.u;
  uint32_t r = (u + 0x7fffu + ((u >> 16) & 1u)) >> 16;  // RNE
  return (ushort)r;
}
__device__ __forceinline__ float bf2f(ushort h) {
  union { uint32_t u; float f; } v; v.u = ((uint32_t)h) << 16;
  return v.f;
}

// ---- fp8 e4m3 (OCP) encode/decode ----
__device__ __forceinline__ uint8_t enc_fp8(float f) {
#if __has_builtin(__builtin_amdgcn_cvt_pk_fp8_f32)
  int r = __builtin_amdgcn_cvt_pk_fp8_f32(f, f, 0, false);
  return (uint8_t)(r & 0xff);
#else
  __hip_fp8_e4m3 t(f);
  return t.__x;
#endif
}
__device__ __forceinline__ float dec_fp8_byte(uint32_t b) {
  uint32_t e = (b >> 3) & 15u, m = b & 7u, s = (b & 0x80u) << 24;
  union { uint32_t u; float f; } n; n.u = s | ((e + 120u) << 23) | (m << 20);
  union { uint32_t u; float f; } d; d.f = (float)m * 0x1p-9f; d.u |= s;
  return e ? n.f : d.f;
}

// decode 4 fp8 bytes in dword v, accumulate into a[0..3] with weight w
__device__ __forceinline__ void acc_fp8x4(float* a, uint32_t v, float w) {
#if __has_builtin(__builtin_amdgcn_cvt_pk_f32_fp8)
  f32x2 lo = __builtin_amdgcn_cvt_pk_f32_fp8(v, false);
  f32x2 hi = __builtin_amdgcn_cvt_pk_f32_fp8(v, true);
  a[0] += w * lo[0]; a[1] += w * lo[1]; a[2] += w * hi[0]; a[3] += w * hi[1];
#else
  a[0] += w * dec_fp8_byte(v & 0xffu);
  a[1] += w * dec_fp8_byte((v >> 8) & 0xffu);
  a[2] += w * dec_fp8_byte((v >> 16) & 0xffu);
  a[3] += w * dec_fp8_byte(v >> 24);
#endif
}

// decode 2 bf16 in dword v, accumulate into a[0..1] with weight w
__device__ __forceinline__ void acc_bf16x2(float* a, uint32_t v, float w) {
  a[0] += w * bf2f((ushort)(v & 0xffffu));
  a[1] += w * bf2f((ushort)(v >> 16));
}

__device__ __forceinline__ void conv8(const float* __restrict__ in,
                                      ushort* __restrict__ out, long idx) {
  const float4* p = (const float4*)(in + idx);
  float4 a = p[0], b = p[1];
  short8 o;
  o[0] = f2bf(a.x); o[1] = f2bf(a.y); o[2] = f2bf(a.z); o[3] = f2bf(a.w);
  o[4] = f2bf(b.x); o[5] = f2bf(b.y); o[6] = f2bf(b.z); o[7] = f2bf(b.w);
  *(short8*)(out + idx) = o;
}

// async global->LDS, 16B per lane; lds base must be wave-uniform
__device__ __forceinline__ void gload_lds16(const void* g, void* lds) {
  __builtin_amdgcn_global_load_lds(
      (const __attribute__((address_space(1))) void*)g,
      (__attribute__((address_space(3))) void*)lds,
      16, 0, 0);
}

// ---------------- fused prep ----------------
// blocks [0,64): LDS-range histogram + rank capture (NO global atomics):
//   block r owns nodes [r*784, r*784+784); scans all edges; LDS atomicAdd
//   gives rank (block-local = globally correct since ranges are disjoint).
// blocks [64, ...): bf16 conversions of x, W1, W2.
__global__ __launch_bounds__(256) void k_prep(const float* __restrict__ x,
                                              ushort* __restrict__ xb,
                                              const float* __restrict__ W1,
                                              ushort* __restrict__ w1b,
                                              const float* __restrict__ W2,
                                              ushort* __restrict__ w2b,
                                              const int* __restrict__ src,
                                              int* __restrict__ deg,
                                              int* __restrict__ rank) {
  __shared__ int hcnt[NODES_PER_HB];
  int b = blockIdx.x, t = threadIdx.x;
  if (b < HIST_BLOCKS) {
    int lo = b * NODES_PER_HB;
    int hi = min(lo + NODES_PER_HB, N_NODES);
    int cntn = hi - lo;
    for (int j = t; j < NODES_PER_HB; j += 256) hcnt[j] = 0;
    __syncthreads();
    const int4* src4 = (const int4*)src;
    for (int i = t; i < N_EDGES / 4; i += 256) {
      int4 s4 = src4[i];
      int e = i * 4;
      if (s4.x >= lo && s4.x < hi) rank[e]     = atomicAdd(&hcnt[s4.x - lo], 1);
      if (s4.y >= lo && s4.y < hi) rank[e + 1] = atomicAdd(&hcnt[s4.y - lo], 1);
      if (s4.z >= lo && s4.z < hi) rank[e + 2] = atomicAdd(&hcnt[s4.z - lo], 1);
      if (s4.w >= lo && s4.w < hi) rank[e + 3] = atomicAdd(&hcnt[s4.w - lo], 1);
    }
    __syncthreads();
    for (int j = t; j < cntn; j += 256) deg[lo + j] = hcnt[j];
  } else if (b < HIST_BLOCKS + CONVX_BLOCKS) {
    long idx = ((long)(b - HIST_BLOCKS) * 256 + t) * 8;
    int row = (int)(idx >> 9);
    if (row < N_NODES) {
      conv8(x, xb, idx);
    } else {
      *(short8*)(xb + idx) = (short8)0;   // zero pad rows
    }
  } else if (b < HIST_BLOCKS + CONVX_BLOCKS + CONVW1_BLOCKS) {
    long idx = ((long)(b - HIST_BLOCKS - CONVX_BLOCKS) * 256 + t) * 8;
    conv8(W1, w1b, idx);
  } else {
    long idx = ((long)(b - HIST_BLOCKS - CONVX_BLOCKS - CONVW1_BLOCKS) * 256 + t) * 8;
    conv8(W2, w2b, idx);
  }
}

// ---------------- CSR segment allocation (unordered segments) ----------------
__global__ __launch_bounds__(256) void k_alloc(const int* __restrict__ deg,
                                               int* __restrict__ rpb,
                                               int* __restrict__ rpe,
                                               int* __restrict__ counter) {
  int i = blockIdx.x * blockDim.x + threadIdx.x;
  int lane = threadIdx.x & 63;
  int d = (i < N_NODES) ? deg[i] : 0;
  int sc = d;
  #pragma unroll
  for (int off = 1; off < 64; off <<= 1) {
    int u = __shfl_up(sc, off, 64);
    if (lane >= off) sc += u;
  }
  int base = 0;
  if (lane == 63) base = atomicAdd(counter, sc);
  base = __shfl(base, 63, 64);
  if (i < N_NODES) {
    int start = base + sc - d;
    rpb[i] = start;
    rpe[i] = start + d;
  }
}

// ---------------- CSR fill: atomic-free, packed 8B records ----------------
__global__ __launch_bounds__(256) void k_fill(const int* __restrict__ src,
                                              const int* __restrict__ dst,
                                              const float* __restrict__ w,
                                              const int* __restrict__ rpb,
                                              const int* __restrict__ rank,
                                              uint2* __restrict__ esw) {
  int e = blockIdx.x * blockDim.x + threadIdx.x;
  if (e < N_EDGES) {
    int pos = rpb[src[e]] + rank[e];
    uint2 p;
    p.x = (unsigned)dst[e];
    p.y = __float_as_uint(w[e]);
    esw[pos] = p;
  }
}

// ---------------- GEMM body: C = A @ B^T + bias (bf16 in, f32 acc, fp8/bf16 out) ----------------
// Staging: global_load_lds width=16, linear LDS dest, inverse-swizzled global source.
// LDS slot s of row r holds global chunk s^(r&7); reads XOR with (r&7) as before.
template <int OUT_FP8>
__device__ __forceinline__ void gemm_body(const ushort* __restrict__ A,
                                          const ushort* __restrict__ B,
                                          const float* __restrict__ bias,
                                          void* __restrict__ Cout,
                                          int K, int Nout, int bm, int bn,
                                          ushort* sA, ushort* sB) {
  const int t = threadIdx.x;
  const int lane = t & 63;
  const int wave = t >> 6;
  const int wr = wave >> 1, wc = wave & 1;

  f32x4 acc[4][4];
  #pragma unroll
  for (int i = 0; i < 4; i++)
    #pragma unroll
    for (int j = 0; j < 4; j++) acc[i][j] = (f32x4)0.f;

  const long a_base = (long)bm * 128 * K;
  const long b_base = (long)bn * 128 * K;

  for (int kt = 0; kt < K; kt += 64) {
    #pragma unroll
    for (int it = 0; it < 4; ++it) {
      int c = it * 256 + t;            // chunk 0..1023 (16B units)
      int r = c >> 3, ccp = c & 7;     // row, slot within row
      int cc = ccp ^ (r & 7);          // global chunk that belongs in this slot
      const ushort* ga = A + a_base + (long)r * K + kt + cc * 8;
      const ushort* gb = B + b_base + (long)r * K + kt + cc * 8;
      char* la = (char*)sA + (it * 256 + wave * 64) * 16;  // wave-uniform
      char* lb = (char*)sB + (it * 256 + wave * 64) * 16;
      gload_lds16(ga, la);
      gload_lds16(gb, lb);
    }
    __syncthreads();
    #pragma unroll
    for (int kk = 0; kk < 2; ++kk) {
      short8 af[4], bfr[4];
      int kchunk = kk * 4 + (lane >> 4);
      #pragma unroll
      for (int mr = 0; mr < 4; ++mr) {
        int row = wr * 64 + mr * 16 + (lane & 15);
        af[mr] = *(const short8*)((const char*)sA + row * 128 +
                                  ((kchunk * 16) ^ ((row & 7) << 4)));
      }
      #pragma unroll
      for (int nr = 0; nr < 4; ++nr) {
        int row = wc * 64 + nr * 16 + (lane & 15);
        bfr[nr] = *(const short8*)((const char*)sB + row * 128 +
                                   ((kchunk * 16) ^ ((row & 7) << 4)));
      }
      #pragma unroll
      for (int mr = 0; mr < 4; ++mr)
        #pragma unroll
        for (int nr = 0; nr < 4; ++nr)
          acc[mr][nr] = __builtin_amdgcn_mfma_f32_16x16x32_bf16(af[mr], bfr[nr],
                                                                acc[mr][nr], 0, 0, 0);
    }
    __syncthreads();
  }

  #pragma unroll
  for (int mr = 0; mr < 4; ++mr)
    #pragma unroll
    for (int nr = 0; nr < 4; ++nr) {
      int col = bn * 128 + wc * 64 + nr * 16 + (lane & 15);
      float bv = bias[col];
      #pragma unroll
      for (int reg = 0; reg < 4; ++reg) {
        int row = bm * 128 + wr * 64 + mr * 16 + (lane >> 4) * 4 + reg;
        float val = acc[mr][nr][reg] + bv;
        if (OUT_FP8) {
          ((uint8_t*)Cout)[(long)row * Nout + col] = enc_fp8(val);
        } else {
          ((ushort*)Cout)[(long)row * Nout + col] = f2bf(val);
        }
      }
    }
}

// ---------------- GEMM layer1 (fp8 out) ----------------
__global__ __launch_bounds__(256) void k_gemm1(const ushort* __restrict__ A,
                                               const ushort* __restrict__ B,
                                               const float* __restrict__ bias,
                                               uint8_t* __restrict__ C) {
  __shared__ ushort sA[128 * 64];
  __shared__ ushort sB[128 * 64];
  int b = blockIdx.x;
  gemm_body<1>(A, B, bias, C, NFEAT, NHID, b % G1_BM, b / G1_BM, sA, sB);
}

// ---------------- GEMM layer2 (bf16 out) ----------------
__global__ __launch_bounds__(256) void k_gemm2(const ushort* __restrict__ A,
                                               const ushort* __restrict__ B,
                                               const float* __restrict__ bias,
                                               ushort* __restrict__ C) {
  __shared__ ushort sA[128 * 64];
  __shared__ ushort sB[128 * 64];
  gemm_body<0>(A, B, bias, C, NHID, NCLASS, blockIdx.x, 0, sA, sB);
}

// ---------------- SpMM layer 1 (+ReLU): fp8 gather -> bf16 out ----------------
// wave per node; 2 edges per wave-step (32 lanes x 16B each); 4-step unroll (8 edges in flight).
__global__ __launch_bounds__(256) void k_spmm1(const int* __restrict__ rpb,
                                               const int* __restrict__ rpe,
                                               const uint2* __restrict__ esw,
                                               const uint8_t* __restrict__ c1,
                                               ushort* __restrict__ h) {
  int node = blockIdx.x * 4 + (threadIdx.x >> 6);   // < MPAD
  int lane = threadIdx.x & 63;
  int half = lane >> 5;
  int col = (lane & 31) * 16;   // fp8 byte/feature offset within row
  float a[16];
  #pragma unroll
  for (int k = 0; k < 16; ++k) a[k] = 0.f;
  if (node < N_NODES) {
    int beg = rpb[node], end = rpe[node];
    for (int j = beg; j < end; j += 8) {
      #pragma unroll
      for (int s = 0; s < 4; ++s) {
        int ei = j + s * 2 + half;
        bool vld = ei < end;
        uint2 p = esw[vld ? ei : 0];
        int d = (int)p.x;
        float w = vld ? __uint_as_float(p.y) : 0.f;
        uint4 q = *(const uint4*)(c1 + (long)d * NHID + col);
        acc_fp8x4(a, q.x, w);      acc_fp8x4(a + 4, q.y, w);
        acc_fp8x4(a + 8, q.z, w);  acc_fp8x4(a + 12, q.w, w);
      }
    }
  }
  #pragma unroll
  for (int k = 0; k < 16; ++k) a[k] += __shfl_xor(a[k], 32, 64);
  if (half == 0) {
    short8 o0, o1;
    #pragma unroll
    for (int k = 0; k < 8; ++k) {
      o0[k] = (short)f2bf(a[k] > 0.f ? a[k] : 0.f);
      o1[k] = (short)f2bf(a[k + 8] > 0.f ? a[k + 8] : 0.f);
    }
    *(short8*)(h + (long)node * NHID + col) = o0;       // pad nodes write zeros
    *(short8*)(h + (long)node * NHID + col + 8) = o1;
  }
}

// ---------------- SpMM layer 2: bf16 gather -> f32 out ----------------
// wave per node; 2 edges per wave-step (32 lanes x 8B = 256B row); 4-step unroll.
__global__ __launch_bounds__(256) void k_spmm2(const int* __restrict__ rpb,
                                               const int* __restrict__ rpe,
                                               const uint2* __restrict__ esw,
                                               const ushort* __restrict__ c2,
                                               float* __restrict__ out) {
  int node = blockIdx.x * 4 + (threadIdx.x >> 6);
  int lane = threadIdx.x & 63;
  int half = lane >> 5;
  int col = (lane & 31) * 4;   // 4 classes per lane
  if (node >= N_NODES) return;
  float a[4] = {0.f, 0.f, 0.f, 0.f};
  int beg = rpb[node], end = rpe[node];
  for (int j = beg; j < end; j += 8) {
    #pragma unroll
    for (int s = 0; s < 4; ++s) {
      int ei = j + s * 2 + half;
      bool vld = ei < end;
      uint2 p = esw[vld ? ei : 0];
      int d = (int)p.x;
      float w = vld ? __uint_as_float(p.y) : 0.f;
      uint2 q = *(const uint2*)(c2 + (long)d * NCLASS + col);
      acc_bf16x2(a, q.x, w);
      acc_bf16x2(a + 2, q.y, w);
    }
  }
  #pragma unroll
  for (int k = 0; k < 4; ++k) a[k] += __shfl_xor(a[k], 32, 64);
  if (half == 0) {
    f32x4 st; st[0] = a[0]; st[1] = a[1]; st[2] = a[2]; st[3] = a[3];
    *(f32x4*)(out + (long)node * NCLASS + col) = st;
  }
}

extern "C" void kernel_launch(void* const* d_in, const int* in_sizes, int n_in,
                              void* d_out, int out_size, void* d_ws, size_t ws_size,
                              hipStream_t stream) {
  const float* x    = (const float*)d_in[0];
  const float* ew   = (const float*)d_in[1];
  const float* W1   = (const float*)d_in[2];
  const float* b1   = (const float*)d_in[3];
  const float* W2   = (const float*)d_in[4];
  const float* b2   = (const float*)d_in[5];
  const int*   esrc = (const int*)d_in[6];
  const int*   edst = (const int*)d_in[7];
  float* out = (float*)d_out;

  char* ws = (char*)d_ws;
  size_t off = 0;
  auto alloc = [&](size_t bytes) -> void* {
    void* p = ws + off;
    off = (off + bytes + 255) & ~(size_t)255;
    return p;
  };

  ushort*  buf0 = (ushort*)alloc((size_t)MPAD * 512 * 2);  // x_bf16, later h_bf16
  uint8_t* c1f8 = (uint8_t*)alloc((size_t)MPAD * 512);     // c1 fp8
  ushort*  c2bf = (ushort*)alloc((size_t)MPAD * 128 * 2);  // c2 bf16
  ushort*  w1b  = (ushort*)alloc((size_t)512 * 512 * 2);
  ushort*  w2b  = (ushort*)alloc((size_t)128 * 512 * 2);
  int*     deg  = (int*)alloc((size_t)N_NODES * 4);
  int*     rpb  = (int*)alloc((size_t)N_NODES * 4);
  int*     rpe  = (int*)alloc((size_t)N_NODES * 4);
  int*     rank = (int*)alloc((size_t)N_EDGES * 4);
  int*     cnt  = (int*)alloc(256);
  uint2*   esw  = (uint2*)alloc((size_t)N_EDGES * 8);

  hipMemsetAsync(cnt, 0, 4, stream);

  // prep: LDS-range histogram (+rank, no global atomics) || convert x/W1/W2
  k_prep<<<HIST_BLOCKS + CONVX_BLOCKS + CONVW1_BLOCKS + CONVW2_BLOCKS, 256, 0, stream>>>(
      x, buf0, W1, w1b, W2, w2b, esrc, deg, rank);
  k_alloc<<<(N_NODES + 255) / 256, 256, 0, stream>>>(deg, rpb, rpe, cnt);

  // CSR fill: atomic-free, packed records
  k_fill<<<FILL_BLOCKS, 256, 0, stream>>>(esrc, edst, ew, rpb, rank, esw);

  // layer-1 linear (fp8 out)
  k_gemm1<<<G1_BLOCKS, 256, 0, stream>>>(buf0, w1b, b1, c1f8);

  // spmm + relu -> h (bf16)
  k_spmm1<<<MPAD / 4, 256, 0, stream>>>(rpb, rpe, esw, c1f8, buf0);

  // layer-2 linear (bf16 out)
  k_gemm2<<<G1_BM, 256, 0, stream>>>(buf0, w2b, b2, c2bf);

  // spmm -> out (f32)
  k_spmm2<<<(N_NODES + 3) / 4, 256, 0, stream>>>(rpb, rpe, esw, c2bf, out);
}

// Round 15
// 249.422 us; speedup vs baseline: 2.1110x; 2.1110x over previous
//
#include <hip/hip_runtime.h>
#include <hip/hip_bf16.h>
#include <hip/hip_fp8.h>
#include <stdint.h>

#define N_NODES 50000
#define N_EDGES 800000
#define NFEAT 512
#define NHID 512
#define NCLASS 128
#define MPAD 50048   // 391 * 128

#define CONVX_BLOCKS 12512   // MPAD*512/8/256
#define CONVW1_BLOCKS 128    // 512*512/8/256
#define CONVW2_BLOCKS 32     // 128*512/8/256
#define HIST_BLOCKS 3125     // 800000/256
#define G1_BM 391
#define G1_BLOCKS 1564       // 391*4
#define FILL_BLOCKS 3125

typedef short short8 __attribute__((ext_vector_type(8)));
typedef float f32x4 __attribute__((ext_vector_type(4)));
typedef float f32x2 __attribute__((ext_vector_type(2)));

__device__ __forceinline__ ushort f2bf(float f) {
  union { float f; uint32_t u; } v; v.f = f;
  uint32_t u = v.u;
  uint32_t r = (u + 0x7fffu + ((u >> 16) & 1u)) >> 16;  // RNE
  return (ushort)r;
}
__device__ __forceinline__ float bf2f(ushort h) {
  union { uint32_t u; float f; } v; v.u = ((uint32_t)h) << 16;
  return v.f;
}

// ---- fp8 e4m3 (OCP) encode/decode ----
__device__ __forceinline__ uint8_t enc_fp8(float f) {
#if __has_builtin(__builtin_amdgcn_cvt_pk_fp8_f32)
  int r = __builtin_amdgcn_cvt_pk_fp8_f32(f, f, 0, false);
  return (uint8_t)(r & 0xff);
#else
  __hip_fp8_e4m3 t(f);
  return t.__x;
#endif
}
__device__ __forceinline__ float dec_fp8_byte(uint32_t b) {
  uint32_t e = (b >> 3) & 15u, m = b & 7u, s = (b & 0x80u) << 24;
  union { uint32_t u; float f; } n; n.u = s | ((e + 120u) << 23) | (m << 20);
  union { uint32_t u; float f; } d; d.f = (float)m * 0x1p-9f; d.u |= s;
  return e ? n.f : d.f;
}

// decode 4 fp8 bytes in dword v, accumulate into a[0..3] with weight w
__device__ __forceinline__ void acc_fp8x4(float* a, uint32_t v, float w) {
#if __has_builtin(__builtin_amdgcn_cvt_pk_f32_fp8)
  f32x2 lo = __builtin_amdgcn_cvt_pk_f32_fp8(v, false);
  f32x2 hi = __builtin_amdgcn_cvt_pk_f32_fp8(v, true);
  a[0] += w * lo[0]; a[1] += w * lo[1]; a[2] += w * hi[0]; a[3] += w * hi[1];
#else
  a[0] += w * dec_fp8_byte(v & 0xffu);
  a[1] += w * dec_fp8_byte((v >> 8) & 0xffu);
  a[2] += w * dec_fp8_byte((v >> 16) & 0xffu);
  a[3] += w * dec_fp8_byte(v >> 24);
#endif
}

// decode 2 bf16 in dword v, accumulate into a[0..1] with weight w
__device__ __forceinline__ void acc_bf16x2(float* a, uint32_t v, float w) {
  a[0] += w * bf2f((ushort)(v & 0xffffu));
  a[1] += w * bf2f((ushort)(v >> 16));
}

__device__ __forceinline__ void conv8(const float* __restrict__ in,
                                      ushort* __restrict__ out, long idx) {
  const float4* p = (const float4*)(in + idx);
  float4 a = p[0], b = p[1];
  short8 o;
  o[0] = f2bf(a.x); o[1] = f2bf(a.y); o[2] = f2bf(a.z); o[3] = f2bf(a.w);
  o[4] = f2bf(b.x); o[5] = f2bf(b.y); o[6] = f2bf(b.z); o[7] = f2bf(b.w);
  *(short8*)(out + idx) = o;
}

// async global->LDS, 16B per lane; lds base must be wave-uniform
__device__ __forceinline__ void gload_lds16(const void* g, void* lds) {
  __builtin_amdgcn_global_load_lds(
      (const __attribute__((address_space(1))) void*)g,
      (__attribute__((address_space(3))) void*)lds,
      16, 0, 0);
}

// ---------------- prep: bf16 conversions only (pure streaming) ----------------
__global__ __launch_bounds__(256) void k_prep(const float* __restrict__ x,
                                              ushort* __restrict__ xb,
                                              const float* __restrict__ W1,
                                              ushort* __restrict__ w1b,
                                              const float* __restrict__ W2,
                                              ushort* __restrict__ w2b) {
  int b = blockIdx.x, t = threadIdx.x;
  if (b < CONVX_BLOCKS) {
    long idx = ((long)b * 256 + t) * 8;
    int row = (int)(idx >> 9);
    if (row < N_NODES) {
      conv8(x, xb, idx);
    } else {
      *(short8*)(xb + idx) = (short8)0;   // zero pad rows
    }
  } else if (b < CONVX_BLOCKS + CONVW1_BLOCKS) {
    long idx = ((long)(b - CONVX_BLOCKS) * 256 + t) * 8;
    conv8(W1, w1b, idx);
  } else {
    long idx = ((long)(b - CONVX_BLOCKS - CONVW1_BLOCKS) * 256 + t) * 8;
    conv8(W2, w2b, idx);
  }
}

// ---------------- CSR segment allocation (unordered segments) ----------------
__global__ __launch_bounds__(256) void k_alloc(const int* __restrict__ deg,
                                               int* __restrict__ rpb,
                                               int* __restrict__ rpe,
                                               int* __restrict__ counter) {
  int i = blockIdx.x * blockDim.x + threadIdx.x;
  int lane = threadIdx.x & 63;
  int d = (i < N_NODES) ? deg[i] : 0;
  int sc = d;
  #pragma unroll
  for (int off = 1; off < 64; off <<= 1) {
    int u = __shfl_up(sc, off, 64);
    if (lane >= off) sc += u;
  }
  int base = 0;
  if (lane == 63) base = atomicAdd(counter, sc);
  base = __shfl(base, 63, 64);
  if (i < N_NODES) {
    int start = base + sc - d;
    rpb[i] = start;
    rpe[i] = start + d;
  }
}

// ---------------- CSR fill: atomic-free, packed 8B records ----------------
__global__ __launch_bounds__(256) void k_fill(const int* __restrict__ src,
                                              const int* __restrict__ dst,
                                              const float* __restrict__ w,
                                              const int* __restrict__ rpb,
                                              const int* __restrict__ rank,
                                              uint2* __restrict__ esw) {
  int e = blockIdx.x * blockDim.x + threadIdx.x;
  if (e < N_EDGES) {
    int pos = rpb[src[e]] + rank[e];
    uint2 p;
    p.x = (unsigned)dst[e];
    p.y = __float_as_uint(w[e]);
    esw[pos] = p;
  }
}

// ---------------- GEMM body: C = A @ B^T + bias (bf16 in, f32 acc, fp8/bf16 out) ----------------
// Staging: global_load_lds width=16, linear LDS dest, inverse-swizzled global source.
// LDS slot s of row r holds global chunk s^(r&7); reads XOR with (r&7) as before.
template <int OUT_FP8>
__device__ __forceinline__ void gemm_body(const ushort* __restrict__ A,
                                          const ushort* __restrict__ B,
                                          const float* __restrict__ bias,
                                          void* __restrict__ Cout,
                                          int K, int Nout, int bm, int bn,
                                          ushort* sA, ushort* sB) {
  const int t = threadIdx.x;
  const int lane = t & 63;
  const int wave = t >> 6;
  const int wr = wave >> 1, wc = wave & 1;

  f32x4 acc[4][4];
  #pragma unroll
  for (int i = 0; i < 4; i++)
    #pragma unroll
    for (int j = 0; j < 4; j++) acc[i][j] = (f32x4)0.f;

  const long a_base = (long)bm * 128 * K;
  const long b_base = (long)bn * 128 * K;

  for (int kt = 0; kt < K; kt += 64) {
    #pragma unroll
    for (int it = 0; it < 4; ++it) {
      int c = it * 256 + t;            // chunk 0..1023 (16B units)
      int r = c >> 3, ccp = c & 7;     // row, slot within row
      int cc = ccp ^ (r & 7);          // global chunk that belongs in this slot
      const ushort* ga = A + a_base + (long)r * K + kt + cc * 8;
      const ushort* gb = B + b_base + (long)r * K + kt + cc * 8;
      char* la = (char*)sA + (it * 256 + wave * 64) * 16;  // wave-uniform
      char* lb = (char*)sB + (it * 256 + wave * 64) * 16;
      gload_lds16(ga, la);
      gload_lds16(gb, lb);
    }
    __syncthreads();
    #pragma unroll
    for (int kk = 0; kk < 2; ++kk) {
      short8 af[4], bfr[4];
      int kchunk = kk * 4 + (lane >> 4);
      #pragma unroll
      for (int mr = 0; mr < 4; ++mr) {
        int row = wr * 64 + mr * 16 + (lane & 15);
        af[mr] = *(const short8*)((const char*)sA + row * 128 +
                                  ((kchunk * 16) ^ ((row & 7) << 4)));
      }
      #pragma unroll
      for (int nr = 0; nr < 4; ++nr) {
        int row = wc * 64 + nr * 16 + (lane & 15);
        bfr[nr] = *(const short8*)((const char*)sB + row * 128 +
                                   ((kchunk * 16) ^ ((row & 7) << 4)));
      }
      #pragma unroll
      for (int mr = 0; mr < 4; ++mr)
        #pragma unroll
        for (int nr = 0; nr < 4; ++nr)
          acc[mr][nr] = __builtin_amdgcn_mfma_f32_16x16x32_bf16(af[mr], bfr[nr],
                                                                acc[mr][nr], 0, 0, 0);
    }
    __syncthreads();
  }

  #pragma unroll
  for (int mr = 0; mr < 4; ++mr)
    #pragma unroll
    for (int nr = 0; nr < 4; ++nr) {
      int col = bn * 128 + wc * 64 + nr * 16 + (lane & 15);
      float bv = bias[col];
      #pragma unroll
      for (int reg = 0; reg < 4; ++reg) {
        int row = bm * 128 + wr * 64 + mr * 16 + (lane >> 4) * 4 + reg;
        float val = acc[mr][nr][reg] + bv;
        if (OUT_FP8) {
          ((uint8_t*)Cout)[(long)row * Nout + col] = enc_fp8(val);
        } else {
          ((ushort*)Cout)[(long)row * Nout + col] = f2bf(val);
        }
      }
    }
}

// ---------------- fused: GEMM layer1 (fp8 out) || degree histogram (+rank) ----------------
// hist's atomic-unit traffic overlaps gemm's MFMA/LDS work (different pipes);
// rank writes are coalesced (unlike round-9's scattered fill stores).
__global__ __launch_bounds__(256) void k_gemm1_hist(const ushort* __restrict__ A,
                                                    const ushort* __restrict__ B,
                                                    const float* __restrict__ bias,
                                                    uint8_t* __restrict__ C,
                                                    const int* __restrict__ src,
                                                    int* __restrict__ deg,
                                                    int* __restrict__ rank) {
  __shared__ ushort sA[128 * 64];
  __shared__ ushort sB[128 * 64];
  int b = blockIdx.x;
  if (b < G1_BLOCKS) {
    gemm_body<1>(A, B, bias, C, NFEAT, NHID, b % G1_BM, b / G1_BM, sA, sB);
  } else {
    int e = (b - G1_BLOCKS) * 256 + threadIdx.x;
    if (e < N_EDGES) rank[e] = atomicAdd(&deg[src[e]], 1);
  }
}

// ---------------- GEMM layer2 (bf16 out) ----------------
__global__ __launch_bounds__(256) void k_gemm2(const ushort* __restrict__ A,
                                               const ushort* __restrict__ B,
                                               const float* __restrict__ bias,
                                               ushort* __restrict__ C) {
  __shared__ ushort sA[128 * 64];
  __shared__ ushort sB[128 * 64];
  gemm_body<0>(A, B, bias, C, NHID, NCLASS, blockIdx.x, 0, sA, sB);
}

// ---------------- SpMM layer 1 (+ReLU): fp8 gather -> bf16 out ----------------
// wave per node; 2 edges per wave-step (32 lanes x 16B each); 4-step unroll (8 edges in flight).
__global__ __launch_bounds__(256) void k_spmm1(const int* __restrict__ rpb,
                                               const int* __restrict__ rpe,
                                               const uint2* __restrict__ esw,
                                               const uint8_t* __restrict__ c1,
                                               ushort* __restrict__ h) {
  int node = blockIdx.x * 4 + (threadIdx.x >> 6);   // < MPAD
  int lane = threadIdx.x & 63;
  int half = lane >> 5;
  int col = (lane & 31) * 16;   // fp8 byte/feature offset within row
  float a[16];
  #pragma unroll
  for (int k = 0; k < 16; ++k) a[k] = 0.f;
  if (node < N_NODES) {
    int beg = rpb[node], end = rpe[node];
    for (int j = beg; j < end; j += 8) {
      #pragma unroll
      for (int s = 0; s < 4; ++s) {
        int ei = j + s * 2 + half;
        bool vld = ei < end;
        uint2 p = esw[vld ? ei : 0];
        int d = (int)p.x;
        float w = vld ? __uint_as_float(p.y) : 0.f;
        uint4 q = *(const uint4*)(c1 + (long)d * NHID + col);
        acc_fp8x4(a, q.x, w);      acc_fp8x4(a + 4, q.y, w);
        acc_fp8x4(a + 8, q.z, w);  acc_fp8x4(a + 12, q.w, w);
      }
    }
  }
  #pragma unroll
  for (int k = 0; k < 16; ++k) a[k] += __shfl_xor(a[k], 32, 64);
  if (half == 0) {
    short8 o0, o1;
    #pragma unroll
    for (int k = 0; k < 8; ++k) {
      o0[k] = (short)f2bf(a[k] > 0.f ? a[k] : 0.f);
      o1[k] = (short)f2bf(a[k + 8] > 0.f ? a[k + 8] : 0.f);
    }
    *(short8*)(h + (long)node * NHID + col) = o0;       // pad nodes write zeros
    *(short8*)(h + (long)node * NHID + col + 8) = o1;
  }
}

// ---------------- SpMM layer 2: bf16 gather -> f32 out ----------------
// wave per node; 2 edges per wave-step (32 lanes x 8B = 256B row); 4-step unroll.
__global__ __launch_bounds__(256) void k_spmm2(const int* __restrict__ rpb,
                                               const int* __restrict__ rpe,
                                               const uint2* __restrict__ esw,
                                               const ushort* __restrict__ c2,
                                               float* __restrict__ out) {
  int node = blockIdx.x * 4 + (threadIdx.x >> 6);
  int lane = threadIdx.x & 63;
  int half = lane >> 5;
  int col = (lane & 31) * 4;   // 4 classes per lane
  if (node >= N_NODES) return;
  float a[4] = {0.f, 0.f, 0.f, 0.f};
  int beg = rpb[node], end = rpe[node];
  for (int j = beg; j < end; j += 8) {
    #pragma unroll
    for (int s = 0; s < 4; ++s) {
      int ei = j + s * 2 + half;
      bool vld = ei < end;
      uint2 p = esw[vld ? ei : 0];
      int d = (int)p.x;
      float w = vld ? __uint_as_float(p.y) : 0.f;
      uint2 q = *(const uint2*)(c2 + (long)d * NCLASS + col);
      acc_bf16x2(a, q.x, w);
      acc_bf16x2(a + 2, q.y, w);
    }
  }
  #pragma unroll
  for (int k = 0; k < 4; ++k) a[k] += __shfl_xor(a[k], 32, 64);
  if (half == 0) {
    f32x4 st; st[0] = a[0]; st[1] = a[1]; st[2] = a[2]; st[3] = a[3];
    *(f32x4*)(out + (long)node * NCLASS + col) = st;
  }
}

extern "C" void kernel_launch(void* const* d_in, const int* in_sizes, int n_in,
                              void* d_out, int out_size, void* d_ws, size_t ws_size,
                              hipStream_t stream) {
  const float* x    = (const float*)d_in[0];
  const float* ew   = (const float*)d_in[1];
  const float* W1   = (const float*)d_in[2];
  const float* b1   = (const float*)d_in[3];
  const float* W2   = (const float*)d_in[4];
  const float* b2   = (const float*)d_in[5];
  const int*   esrc = (const int*)d_in[6];
  const int*   edst = (const int*)d_in[7];
  float* out = (float*)d_out;

  char* ws = (char*)d_ws;
  size_t off = 0;
  auto alloc = [&](size_t bytes) -> void* {
    void* p = ws + off;
    off = (off + bytes + 255) & ~(size_t)255;
    return p;
  };

  ushort*  buf0 = (ushort*)alloc((size_t)MPAD * 512 * 2);  // x_bf16, later h_bf16
  uint8_t* c1f8 = (uint8_t*)alloc((size_t)MPAD * 512);     // c1 fp8
  ushort*  c2bf = (ushort*)alloc((size_t)MPAD * 128 * 2);  // c2 bf16
  ushort*  w1b  = (ushort*)alloc((size_t)512 * 512 * 2);
  ushort*  w2b  = (ushort*)alloc((size_t)128 * 512 * 2);
  int*     deg  = (int*)alloc((size_t)N_NODES * 4);
  int*     rpb  = (int*)alloc((size_t)N_NODES * 4);
  int*     rpe  = (int*)alloc((size_t)N_NODES * 4);
  int*     rank = (int*)alloc((size_t)N_EDGES * 4);
  int*     cnt  = (int*)alloc(256);
  uint2*   esw  = (uint2*)alloc((size_t)N_EDGES * 8);

  hipMemsetAsync(deg, 0, (size_t)N_NODES * 4, stream);
  hipMemsetAsync(cnt, 0, 4, stream);

  // prep: convert x/W1/W2 to bf16 (pure streaming)
  k_prep<<<CONVX_BLOCKS + CONVW1_BLOCKS + CONVW2_BLOCKS, 256, 0, stream>>>(
      x, buf0, W1, w1b, W2, w2b);

  // layer-1 linear (fp8 out)  ||  degree histogram + rank capture
  k_gemm1_hist<<<G1_BLOCKS + HIST_BLOCKS, 256, 0, stream>>>(
      buf0, w1b, b1, c1f8, esrc, deg, rank);

  k_alloc<<<(N_NODES + 255) / 256, 256, 0, stream>>>(deg, rpb, rpe, cnt);

  // CSR fill: atomic-free, packed records
  k_fill<<<FILL_BLOCKS, 256, 0, stream>>>(esrc, edst, ew, rpb, rank, esw);

  // spmm + relu -> h (bf16)
  k_spmm1<<<MPAD / 4, 256, 0, stream>>>(rpb, rpe, esw, c1f8, buf0);

  // layer-2 linear (bf16 out)
  k_gemm2<<<G1_BM, 256, 0, stream>>>(buf0, w2b, b2, c2bf);

  // spmm -> out (f32)
  k_spmm2<<<(N_NODES + 3) / 4, 256, 0, stream>>>(rpb, rpe, esw, c2bf, out);
}

// Round 16
// 246.799 us; speedup vs baseline: 2.1335x; 1.0106x over previous
//
#include <hip/hip_runtime.h>
#include <hip/hip_bf16.h>
#include <hip/hip_fp8.h>
#include <stdint.h>

#define N_NODES 50000
#define N_EDGES 800000
#define NFEAT 512
#define NHID 512
#define NCLASS 128
#define MPAD 50048   // 391 * 128

#define CONVW1_BLOCKS 128    // 512*512/8/256
#define CONVW2_BLOCKS 32     // 128*512/8/256
#define HIST_BLOCKS 3125     // 800000/256
#define G1_BM 391
#define G1_BLOCKS 1564       // 391*4
#define G1H_BLOCKS 4692      // 1564*3  ({gemm,hist,hist} interleave)
#define FILL_BLOCKS 3125

typedef short short8 __attribute__((ext_vector_type(8)));
typedef float f32x4 __attribute__((ext_vector_type(4)));
typedef float f32x2 __attribute__((ext_vector_type(2)));

__device__ __forceinline__ ushort f2bf(float f) {
  union { float f; uint32_t u; } v; v.f = f;
  uint32_t u = v.u;
  uint32_t r = (u + 0x7fffu + ((u >> 16) & 1u)) >> 16;  // RNE
  return (ushort)r;
}
__device__ __forceinline__ float bf2f(ushort h) {
  union { uint32_t u; float f; } v; v.u = ((uint32_t)h) << 16;
  return v.f;
}

// ---- fp8 e4m3 (OCP) encode/decode ----
__device__ __forceinline__ uint8_t enc_fp8(float f) {
#if __has_builtin(__builtin_amdgcn_cvt_pk_fp8_f32)
  int r = __builtin_amdgcn_cvt_pk_fp8_f32(f, f, 0, false);
  return (uint8_t)(r & 0xff);
#else
  __hip_fp8_e4m3 t(f);
  return t.__x;
#endif
}
__device__ __forceinline__ float dec_fp8_byte(uint32_t b) {
  uint32_t e = (b >> 3) & 15u, m = b & 7u, s = (b & 0x80u) << 24;
  union { uint32_t u; float f; } n; n.u = s | ((e + 120u) << 23) | (m << 20);
  union { uint32_t u; float f; } d; d.f = (float)m * 0x1p-9f; d.u |= s;
  return e ? n.f : d.f;
}

// decode 4 fp8 bytes in dword v, accumulate into a[0..3] with weight w
__device__ __forceinline__ void acc_fp8x4(float* a, uint32_t v, float w) {
#if __has_builtin(__builtin_amdgcn_cvt_pk_f32_fp8)
  f32x2 lo = __builtin_amdgcn_cvt_pk_f32_fp8(v, false);
  f32x2 hi = __builtin_amdgcn_cvt_pk_f32_fp8(v, true);
  a[0] += w * lo[0]; a[1] += w * lo[1]; a[2] += w * hi[0]; a[3] += w * hi[1];
#else
  a[0] += w * dec_fp8_byte(v & 0xffu);
  a[1] += w * dec_fp8_byte((v >> 8) & 0xffu);
  a[2] += w * dec_fp8_byte((v >> 16) & 0xffu);
  a[3] += w * dec_fp8_byte(v >> 24);
#endif
}

// decode 2 bf16 in dword v, accumulate into a[0..1] with weight w
__device__ __forceinline__ void acc_bf16x2(float* a, uint32_t v, float w) {
  a[0] += w * bf2f((ushort)(v & 0xffffu));
  a[1] += w * bf2f((ushort)(v >> 16));
}

__device__ __forceinline__ void conv8(const float* __restrict__ in,
                                      ushort* __restrict__ out, long idx) {
  const float4* p = (const float4*)(in + idx);
  float4 a = p[0], b = p[1];
  short8 o;
  o[0] = f2bf(a.x); o[1] = f2bf(a.y); o[2] = f2bf(a.z); o[3] = f2bf(a.w);
  o[4] = f2bf(b.x); o[5] = f2bf(b.y); o[6] = f2bf(b.z); o[7] = f2bf(b.w);
  *(short8*)(out + idx) = o;
}

// async global->LDS, 16B per lane; lds base must be wave-uniform
__device__ __forceinline__ void gload_lds16(const void* g, void* lds) {
  __builtin_amdgcn_global_load_lds(
      (const __attribute__((address_space(1))) void*)g,
      (__attribute__((address_space(3))) void*)lds,
      16, 0, 0);
}

// ---------------- prep: W1/W2 bf16 conversion only (tiny) ----------------
__global__ __launch_bounds__(256) void k_prepw(const float* __restrict__ W1,
                                               ushort* __restrict__ w1b,
                                               const float* __restrict__ W2,
                                               ushort* __restrict__ w2b) {
  int b = blockIdx.x, t = threadIdx.x;
  if (b < CONVW1_BLOCKS) {
    long idx = ((long)b * 256 + t) * 8;
    conv8(W1, w1b, idx);
  } else {
    long idx = ((long)(b - CONVW1_BLOCKS) * 256 + t) * 8;
    conv8(W2, w2b, idx);
  }
}

// ---------------- CSR segment allocation (unordered segments) ----------------
__global__ __launch_bounds__(256) void k_alloc(const int* __restrict__ deg,
                                               int* __restrict__ rpb,
                                               int* __restrict__ rpe,
                                               int* __restrict__ counter) {
  int i = blockIdx.x * blockDim.x + threadIdx.x;
  int lane = threadIdx.x & 63;
  int d = (i < N_NODES) ? deg[i] : 0;
  int sc = d;
  #pragma unroll
  for (int off = 1; off < 64; off <<= 1) {
    int u = __shfl_up(sc, off, 64);
    if (lane >= off) sc += u;
  }
  int base = 0;
  if (lane == 63) base = atomicAdd(counter, sc);
  base = __shfl(base, 63, 64);
  if (i < N_NODES) {
    int start = base + sc - d;
    rpb[i] = start;
    rpe[i] = start + d;
  }
}

// ---------------- CSR fill: atomic-free, packed 8B records ----------------
__global__ __launch_bounds__(256) void k_fill(const int* __restrict__ src,
                                              const int* __restrict__ dst,
                                              const float* __restrict__ w,
                                              const int* __restrict__ rpb,
                                              const int* __restrict__ rank,
                                              uint2* __restrict__ esw) {
  int e = blockIdx.x * blockDim.x + threadIdx.x;
  if (e < N_EDGES) {
    int pos = rpb[src[e]] + rank[e];
    uint2 p;
    p.x = (unsigned)dst[e];
    p.y = __float_as_uint(w[e]);
    esw[pos] = p;
  }
}

// ---------------- GEMM1 body: C_fp8 = bf16(x_f32) @ w1b^T + b1 ----------------
// A: reg-staged from f32 x with in-register f2bf (pad rows -> 0); swizzled ds_write.
// B: global_load_lds width=16, linear LDS dest, inverse-swizzled global source.
__device__ __forceinline__ void gemm1_body(const float* __restrict__ X,
                                           const ushort* __restrict__ B,
                                           const float* __restrict__ bias,
                                           uint8_t* __restrict__ Cout,
                                           int bm, int bn,
                                           ushort* sA, ushort* sB) {
  const int K = NFEAT, Nout = NHID;
  const int t = threadIdx.x;
  const int lane = t & 63;
  const int wave = t >> 6;
  const int wr = wave >> 1, wc = wave & 1;

  f32x4 acc[4][4];
  #pragma unroll
  for (int i = 0; i < 4; i++)
    #pragma unroll
    for (int j = 0; j < 4; j++) acc[i][j] = (f32x4)0.f;

  const long b_base = (long)bn * 128 * K;

  for (int kt = 0; kt < K; kt += 64) {
    #pragma unroll
    for (int it = 0; it < 4; ++it) {
      int c = it * 256 + t;            // chunk 0..1023 (8-element units)
      int r = c >> 3;
      // B: slot ccp gets global chunk ccp^(r&7) via gload_lds (linear dest)
      int ccp = c & 7;
      int ccg = ccp ^ (r & 7);
      gload_lds16(B + b_base + (long)r * K + kt + ccg * 8,
                  (char*)sB + (it * 256 + wave * 64) * 16);
      // A: global chunk cc from f32 x -> cvt -> swizzled slot cc^(r&7)
      int cc = c & 7;
      long grow = (long)bm * 128 + r;
      short8 o = (short8)0;
      if (grow < N_NODES) {
        const float4* p = (const float4*)(X + grow * NFEAT + kt + cc * 8);
        float4 va = p[0], vb = p[1];
        o[0] = f2bf(va.x); o[1] = f2bf(va.y); o[2] = f2bf(va.z); o[3] = f2bf(va.w);
        o[4] = f2bf(vb.x); o[5] = f2bf(vb.y); o[6] = f2bf(vb.z); o[7] = f2bf(vb.w);
      }
      *(short8*)((char*)sA + r * 128 + ((cc ^ (r & 7)) * 16)) = o;
    }
    __syncthreads();
    #pragma unroll
    for (int kk = 0; kk < 2; ++kk) {
      short8 af[4], bfr[4];
      int kchunk = kk * 4 + (lane >> 4);
      #pragma unroll
      for (int mr = 0; mr < 4; ++mr) {
        int row = wr * 64 + mr * 16 + (lane & 15);
        af[mr] = *(const short8*)((const char*)sA + row * 128 +
                                  ((kchunk * 16) ^ ((row & 7) << 4)));
      }
      #pragma unroll
      for (int nr = 0; nr < 4; ++nr) {
        int row = wc * 64 + nr * 16 + (lane & 15);
        bfr[nr] = *(const short8*)((const char*)sB + row * 128 +
                                   ((kchunk * 16) ^ ((row & 7) << 4)));
      }
      #pragma unroll
      for (int mr = 0; mr < 4; ++mr)
        #pragma unroll
        for (int nr = 0; nr < 4; ++nr)
          acc[mr][nr] = __builtin_amdgcn_mfma_f32_16x16x32_bf16(af[mr], bfr[nr],
                                                                acc[mr][nr], 0, 0, 0);
    }
    __syncthreads();
  }

  #pragma unroll
  for (int mr = 0; mr < 4; ++mr)
    #pragma unroll
    for (int nr = 0; nr < 4; ++nr) {
      int col = bn * 128 + wc * 64 + nr * 16 + (lane & 15);
      float bv = bias[col];
      #pragma unroll
      for (int reg = 0; reg < 4; ++reg) {
        int row = bm * 128 + wr * 64 + mr * 16 + (lane >> 4) * 4 + reg;
        Cout[(long)row * Nout + col] = enc_fp8(acc[mr][nr][reg] + bv);
      }
    }
}

// ---------------- GEMM body (bf16 A via gload_lds) for layer 2 ----------------
__device__ __forceinline__ void gemm_body_bf(const ushort* __restrict__ A,
                                             const ushort* __restrict__ B,
                                             const float* __restrict__ bias,
                                             ushort* __restrict__ Cout,
                                             int K, int Nout, int bm, int bn,
                                             ushort* sA, ushort* sB) {
  const int t = threadIdx.x;
  const int lane = t & 63;
  const int wave = t >> 6;
  const int wr = wave >> 1, wc = wave & 1;

  f32x4 acc[4][4];
  #pragma unroll
  for (int i = 0; i < 4; i++)
    #pragma unroll
    for (int j = 0; j < 4; j++) acc[i][j] = (f32x4)0.f;

  const long a_base = (long)bm * 128 * K;
  const long b_base = (long)bn * 128 * K;

  for (int kt = 0; kt < K; kt += 64) {
    #pragma unroll
    for (int it = 0; it < 4; ++it) {
      int c = it * 256 + t;
      int r = c >> 3, ccp = c & 7;
      int cc = ccp ^ (r & 7);
      gload_lds16(A + a_base + (long)r * K + kt + cc * 8,
                  (char*)sA + (it * 256 + wave * 64) * 16);
      gload_lds16(B + b_base + (long)r * K + kt + cc * 8,
                  (char*)sB + (it * 256 + wave * 64) * 16);
    }
    __syncthreads();
    #pragma unroll
    for (int kk = 0; kk < 2; ++kk) {
      short8 af[4], bfr[4];
      int kchunk = kk * 4 + (lane >> 4);
      #pragma unroll
      for (int mr = 0; mr < 4; ++mr) {
        int row = wr * 64 + mr * 16 + (lane & 15);
        af[mr] = *(const short8*)((const char*)sA + row * 128 +
                                  ((kchunk * 16) ^ ((row & 7) << 4)));
      }
      #pragma unroll
      for (int nr = 0; nr < 4; ++nr) {
        int row = wc * 64 + nr * 16 + (lane & 15);
        bfr[nr] = *(const short8*)((const char*)sB + row * 128 +
                                   ((kchunk * 16) ^ ((row & 7) << 4)));
      }
      #pragma unroll
      for (int mr = 0; mr < 4; ++mr)
        #pragma unroll
        for (int nr = 0; nr < 4; ++nr)
          acc[mr][nr] = __builtin_amdgcn_mfma_f32_16x16x32_bf16(af[mr], bfr[nr],
                                                                acc[mr][nr], 0, 0, 0);
    }
    __syncthreads();
  }

  #pragma unroll
  for (int mr = 0; mr < 4; ++mr)
    #pragma unroll
    for (int nr = 0; nr < 4; ++nr) {
      int col = bn * 128 + wc * 64 + nr * 16 + (lane & 15);
      float bv = bias[col];
      #pragma unroll
      for (int reg = 0; reg < 4; ++reg) {
        int row = bm * 128 + wr * 64 + mr * 16 + (lane >> 4) * 4 + reg;
        Cout[(long)row * Nout + col] = f2bf(acc[mr][nr][reg] + bv);
      }
    }
}

// ---------------- fused: GEMM layer1 (f32 A, fp8 out) interleaved 1:2 with hist ----------------
// pattern {gemm,hist,hist}: hist atomics overlap GEMM from t=0; bm-major so x is HBM-read once.
__global__ __launch_bounds__(256) void k_gemm1_hist(const float* __restrict__ X,
                                                    const ushort* __restrict__ B,
                                                    const float* __restrict__ bias,
                                                    uint8_t* __restrict__ C,
                                                    const int* __restrict__ src,
                                                    int* __restrict__ deg,
                                                    int* __restrict__ rank) {
  __shared__ ushort sA[128 * 64];
  __shared__ ushort sB[128 * 64];
  int b = blockIdx.x;
  int g = b / 3, rem = b - g * 3;
  if (rem == 0) {
    gemm1_body(X, B, bias, C, g >> 2, g & 3, sA, sB);   // bm-major
  } else {
    int e = (g * 2 + rem - 1) * 256 + threadIdx.x;
    if (e < N_EDGES) rank[e] = atomicAdd(&deg[src[e]], 1);
  }
}

// ---------------- GEMM layer2 (bf16 out) ----------------
__global__ __launch_bounds__(256) void k_gemm2(const ushort* __restrict__ A,
                                               const ushort* __restrict__ B,
                                               const float* __restrict__ bias,
                                               ushort* __restrict__ C) {
  __shared__ ushort sA[128 * 64];
  __shared__ ushort sB[128 * 64];
  gemm_body_bf(A, B, bias, C, NHID, NCLASS, blockIdx.x, 0, sA, sB);
}

// ---------------- SpMM layer 1 (+ReLU): fp8 gather -> bf16 out ----------------
// wave per node; 2 edges per wave-step (32 lanes x 16B each); 4-step unroll (8 edges in flight).
__global__ __launch_bounds__(256) void k_spmm1(const int* __restrict__ rpb,
                                               const int* __restrict__ rpe,
                                               const uint2* __restrict__ esw,
                                               const uint8_t* __restrict__ c1,
                                               ushort* __restrict__ h) {
  int node = blockIdx.x * 4 + (threadIdx.x >> 6);   // < MPAD
  int lane = threadIdx.x & 63;
  int half = lane >> 5;
  int col = (lane & 31) * 16;   // fp8 byte/feature offset within row
  float a[16];
  #pragma unroll
  for (int k = 0; k < 16; ++k) a[k] = 0.f;
  if (node < N_NODES) {
    int beg = rpb[node], end = rpe[node];
    for (int j = beg; j < end; j += 8) {
      #pragma unroll
      for (int s = 0; s < 4; ++s) {
        int ei = j + s * 2 + half;
        bool vld = ei < end;
        uint2 p = esw[vld ? ei : 0];
        int d = (int)p.x;
        float w = vld ? __uint_as_float(p.y) : 0.f;
        uint4 q = *(const uint4*)(c1 + (long)d * NHID + col);
        acc_fp8x4(a, q.x, w);      acc_fp8x4(a + 4, q.y, w);
        acc_fp8x4(a + 8, q.z, w);  acc_fp8x4(a + 12, q.w, w);
      }
    }
  }
  #pragma unroll
  for (int k = 0; k < 16; ++k) a[k] += __shfl_xor(a[k], 32, 64);
  if (half == 0) {
    short8 o0, o1;
    #pragma unroll
    for (int k = 0; k < 8; ++k) {
      o0[k] = (short)f2bf(a[k] > 0.f ? a[k] : 0.f);
      o1[k] = (short)f2bf(a[k + 8] > 0.f ? a[k + 8] : 0.f);
    }
    *(short8*)(h + (long)node * NHID + col) = o0;       // pad nodes write zeros
    *(short8*)(h + (long)node * NHID + col + 8) = o1;
  }
}

// ---------------- SpMM layer 2: bf16 gather -> f32 out ----------------
// wave per node; 2 edges per wave-step (32 lanes x 8B = 256B row); 4-step unroll.
__global__ __launch_bounds__(256) void k_spmm2(const int* __restrict__ rpb,
                                               const int* __restrict__ rpe,
                                               const uint2* __restrict__ esw,
                                               const ushort* __restrict__ c2,
                                               float* __restrict__ out) {
  int node = blockIdx.x * 4 + (threadIdx.x >> 6);
  int lane = threadIdx.x & 63;
  int half = lane >> 5;
  int col = (lane & 31) * 4;   // 4 classes per lane
  if (node >= N_NODES) return;
  float a[4] = {0.f, 0.f, 0.f, 0.f};
  int beg = rpb[node], end = rpe[node];
  for (int j = beg; j < end; j += 8) {
    #pragma unroll
    for (int s = 0; s < 4; ++s) {
      int ei = j + s * 2 + half;
      bool vld = ei < end;
      uint2 p = esw[vld ? ei : 0];
      int d = (int)p.x;
      float w = vld ? __uint_as_float(p.y) : 0.f;
      uint2 q = *(const uint2*)(c2 + (long)d * NCLASS + col);
      acc_bf16x2(a, q.x, w);
      acc_bf16x2(a + 2, q.y, w);
    }
  }
  #pragma unroll
  for (int k = 0; k < 4; ++k) a[k] += __shfl_xor(a[k], 32, 64);
  if (half == 0) {
    f32x4 st; st[0] = a[0]; st[1] = a[1]; st[2] = a[2]; st[3] = a[3];
    *(f32x4*)(out + (long)node * NCLASS + col) = st;
  }
}

extern "C" void kernel_launch(void* const* d_in, const int* in_sizes, int n_in,
                              void* d_out, int out_size, void* d_ws, size_t ws_size,
                              hipStream_t stream) {
  const float* x    = (const float*)d_in[0];
  const float* ew   = (const float*)d_in[1];
  const float* W1   = (const float*)d_in[2];
  const float* b1   = (const float*)d_in[3];
  const float* W2   = (const float*)d_in[4];
  const float* b2   = (const float*)d_in[5];
  const int*   esrc = (const int*)d_in[6];
  const int*   edst = (const int*)d_in[7];
  float* out = (float*)d_out;

  char* ws = (char*)d_ws;
  size_t off = 0;
  auto alloc = [&](size_t bytes) -> void* {
    void* p = ws + off;
    off = (off + bytes + 255) & ~(size_t)255;
    return p;
  };

  ushort*  hbuf = (ushort*)alloc((size_t)MPAD * 512 * 2);  // h bf16 (after spmm1)
  uint8_t* c1f8 = (uint8_t*)alloc((size_t)MPAD * 512);     // c1 fp8
  ushort*  c2bf = (ushort*)alloc((size_t)MPAD * 128 * 2);  // c2 bf16
  ushort*  w1b  = (ushort*)alloc((size_t)512 * 512 * 2);
  ushort*  w2b  = (ushort*)alloc((size_t)128 * 512 * 2);
  int*     deg  = (int*)alloc((size_t)N_NODES * 4);
  int*     rpb  = (int*)alloc((size_t)N_NODES * 4);
  int*     rpe  = (int*)alloc((size_t)N_NODES * 4);
  int*     rank = (int*)alloc((size_t)N_EDGES * 4);
  int*     cnt  = (int*)alloc(256);
  uint2*   esw  = (uint2*)alloc((size_t)N_EDGES * 8);

  hipMemsetAsync(deg, 0, (size_t)N_NODES * 4, stream);
  hipMemsetAsync(cnt, 0, 4, stream);

  // prep: convert W1/W2 to bf16 (tiny)
  k_prepw<<<CONVW1_BLOCKS + CONVW2_BLOCKS, 256, 0, stream>>>(W1, w1b, W2, w2b);

  // layer-1 linear (f32 A in-register cvt, fp8 out)  interleaved with  hist(+rank)
  k_gemm1_hist<<<G1H_BLOCKS, 256, 0, stream>>>(x, w1b, b1, c1f8, esrc, deg, rank);

  k_alloc<<<(N_NODES + 255) / 256, 256, 0, stream>>>(deg, rpb, rpe, cnt);

  // CSR fill: atomic-free, packed records
  k_fill<<<FILL_BLOCKS, 256, 0, stream>>>(esrc, edst, ew, rpb, rank, esw);

  // spmm + relu -> h (bf16)
  k_spmm1<<<MPAD / 4, 256, 0, stream>>>(rpb, rpe, esw, c1f8, hbuf);

  // layer-2 linear (bf16 out)
  k_gemm2<<<G1_BM, 256, 0, stream>>>(hbuf, w2b, b2, c2bf);

  // spmm -> out (f32)
  k_spmm2<<<(N_NODES + 3) / 4, 256, 0, stream>>>(rpb, rpe, esw, c2bf, out);
}

// Round 17
// 237.875 us; speedup vs baseline: 2.2135x; 1.0375x over previous
//
#include <hip/hip_runtime.h>
#include <hip/hip_bf16.h>
#include <hip/hip_fp8.h>
#include <stdint.h>

#define N_NODES 50000
#define N_EDGES 800000
#define NFEAT 512
#define NHID 512
#define NCLASS 128
#define MPAD 50048   // 391 * 128

#define CONVW1_BLOCKS 128    // 512*512/8/256
#define CONVW2_BLOCKS 32     // 128*512/8/256
#define G1_BM 391
#define G1H_GROUPS 1568      // 8*196 (padded so each XCD gets 196 gemm blocks)
#define G1H_BLOCKS 4704      // 3*1568  ({gemm,hist,hist} interleave)
#define FILL_BLOCKS 3125

typedef short short8 __attribute__((ext_vector_type(8)));
typedef float f32x4 __attribute__((ext_vector_type(4)));
typedef float f32x2 __attribute__((ext_vector_type(2)));

__device__ __forceinline__ ushort f2bf(float f) {
  union { float f; uint32_t u; } v; v.f = f;
  uint32_t u = v.u;
  uint32_t r = (u + 0x7fffu + ((u >> 16) & 1u)) >> 16;  // RNE
  return (ushort)r;
}
__device__ __forceinline__ float bf2f(ushort h) {
  union { uint32_t u; float f; } v; v.u = ((uint32_t)h) << 16;
  return v.f;
}

// ---- fp8 e4m3 (OCP) encode/decode ----
__device__ __forceinline__ uint8_t enc_fp8(float f) {
#if __has_builtin(__builtin_amdgcn_cvt_pk_fp8_f32)
  int r = __builtin_amdgcn_cvt_pk_fp8_f32(f, f, 0, false);
  return (uint8_t)(r & 0xff);
#else
  __hip_fp8_e4m3 t(f);
  return t.__x;
#endif
}
__device__ __forceinline__ float dec_fp8_byte(uint32_t b) {
  uint32_t e = (b >> 3) & 15u, m = b & 7u, s = (b & 0x80u) << 24;
  union { uint32_t u; float f; } n; n.u = s | ((e + 120u) << 23) | (m << 20);
  union { uint32_t u; float f; } d; d.f = (float)m * 0x1p-9f; d.u |= s;
  return e ? n.f : d.f;
}

// decode 4 fp8 bytes in dword v, accumulate into a[0..3] with weight w
__device__ __forceinline__ void acc_fp8x4(float* a, uint32_t v, float w) {
#if __has_builtin(__builtin_amdgcn_cvt_pk_f32_fp8)
  f32x2 lo = __builtin_amdgcn_cvt_pk_f32_fp8(v, false);
  f32x2 hi = __builtin_amdgcn_cvt_pk_f32_fp8(v, true);
  a[0] += w * lo[0]; a[1] += w * lo[1]; a[2] += w * hi[0]; a[3] += w * hi[1];
#else
  a[0] += w * dec_fp8_byte(v & 0xffu);
  a[1] += w * dec_fp8_byte((v >> 8) & 0xffu);
  a[2] += w * dec_fp8_byte((v >> 16) & 0xffu);
  a[3] += w * dec_fp8_byte(v >> 24);
#endif
}

// decode 2 bf16 in dword v, accumulate into a[0..1] with weight w
__device__ __forceinline__ void acc_bf16x2(float* a, uint32_t v, float w) {
  a[0] += w * bf2f((ushort)(v & 0xffffu));
  a[1] += w * bf2f((ushort)(v >> 16));
}

__device__ __forceinline__ void conv8(const float* __restrict__ in,
                                      ushort* __restrict__ out, long idx) {
  const float4* p = (const float4*)(in + idx);
  float4 a = p[0], b = p[1];
  short8 o;
  o[0] = f2bf(a.x); o[1] = f2bf(a.y); o[2] = f2bf(a.z); o[3] = f2bf(a.w);
  o[4] = f2bf(b.x); o[5] = f2bf(b.y); o[6] = f2bf(b.z); o[7] = f2bf(b.w);
  *(short8*)(out + idx) = o;
}

// async global->LDS, 16B per lane; lds base must be wave-uniform
__device__ __forceinline__ void gload_lds16(const void* g, void* lds) {
  __builtin_amdgcn_global_load_lds(
      (const __attribute__((address_space(1))) void*)g,
      (__attribute__((address_space(3))) void*)lds,
      16, 0, 0);
}

// ---------------- prep: W1/W2 bf16 conversion only (tiny) ----------------
__global__ __launch_bounds__(256) void k_prepw(const float* __restrict__ W1,
                                               ushort* __restrict__ w1b,
                                               const float* __restrict__ W2,
                                               ushort* __restrict__ w2b) {
  int b = blockIdx.x, t = threadIdx.x;
  if (b < CONVW1_BLOCKS) {
    long idx = ((long)b * 256 + t) * 8;
    conv8(W1, w1b, idx);
  } else {
    long idx = ((long)(b - CONVW1_BLOCKS) * 256 + t) * 8;
    conv8(W2, w2b, idx);
  }
}

// ---------------- CSR segment allocation (unordered segments) ----------------
__global__ __launch_bounds__(256) void k_alloc(const int* __restrict__ deg,
                                               int* __restrict__ rpb,
                                               int* __restrict__ rpe,
                                               int* __restrict__ counter) {
  int i = blockIdx.x * blockDim.x + threadIdx.x;
  int lane = threadIdx.x & 63;
  int d = (i < N_NODES) ? deg[i] : 0;
  int sc = d;
  #pragma unroll
  for (int off = 1; off < 64; off <<= 1) {
    int u = __shfl_up(sc, off, 64);
    if (lane >= off) sc += u;
  }
  int base = 0;
  if (lane == 63) base = atomicAdd(counter, sc);
  base = __shfl(base, 63, 64);
  if (i < N_NODES) {
    int start = base + sc - d;
    rpb[i] = start;
    rpe[i] = start + d;
  }
}

// ---------------- CSR fill: atomic-free, packed 8B records ----------------
__global__ __launch_bounds__(256) void k_fill(const int* __restrict__ src,
                                              const int* __restrict__ dst,
                                              const float* __restrict__ w,
                                              const int* __restrict__ rpb,
                                              const int* __restrict__ rank,
                                              uint2* __restrict__ esw) {
  int e = blockIdx.x * blockDim.x + threadIdx.x;
  if (e < N_EDGES) {
    int pos = rpb[src[e]] + rank[e];
    uint2 p;
    p.x = (unsigned)dst[e];
    p.y = __float_as_uint(w[e]);
    esw[pos] = p;
  }
}

// ---------------- GEMM1 body: C_fp8 = bf16(x_f32) @ w1b^T + b1 ----------------
// A: reg-staged from f32 x with in-register f2bf (pad rows -> 0); swizzled ds_write.
// B: global_load_lds width=16, linear LDS dest, inverse-swizzled global source.
__device__ __forceinline__ void gemm1_body(const float* __restrict__ X,
                                           const ushort* __restrict__ B,
                                           const float* __restrict__ bias,
                                           uint8_t* __restrict__ Cout,
                                           int bm, int bn,
                                           ushort* sA, ushort* sB) {
  const int K = NFEAT, Nout = NHID;
  const int t = threadIdx.x;
  const int lane = t & 63;
  const int wave = t >> 6;
  const int wr = wave >> 1, wc = wave & 1;

  f32x4 acc[4][4];
  #pragma unroll
  for (int i = 0; i < 4; i++)
    #pragma unroll
    for (int j = 0; j < 4; j++) acc[i][j] = (f32x4)0.f;

  const long b_base = (long)bn * 128 * K;

  for (int kt = 0; kt < K; kt += 64) {
    #pragma unroll
    for (int it = 0; it < 4; ++it) {
      int c = it * 256 + t;            // chunk 0..1023 (8-element units)
      int r = c >> 3;
      // B: slot ccp gets global chunk ccp^(r&7) via gload_lds (linear dest)
      int ccp = c & 7;
      int ccg = ccp ^ (r & 7);
      gload_lds16(B + b_base + (long)r * K + kt + ccg * 8,
                  (char*)sB + (it * 256 + wave * 64) * 16);
      // A: global chunk cc from f32 x -> cvt -> swizzled slot cc^(r&7)
      int cc = c & 7;
      long grow = (long)bm * 128 + r;
      short8 o = (short8)0;
      if (grow < N_NODES) {
        const float4* p = (const float4*)(X + grow * NFEAT + kt + cc * 8);
        float4 va = p[0], vb = p[1];
        o[0] = f2bf(va.x); o[1] = f2bf(va.y); o[2] = f2bf(va.z); o[3] = f2bf(va.w);
        o[4] = f2bf(vb.x); o[5] = f2bf(vb.y); o[6] = f2bf(vb.z); o[7] = f2bf(vb.w);
      }
      *(short8*)((char*)sA + r * 128 + ((cc ^ (r & 7)) * 16)) = o;
    }
    __syncthreads();
    #pragma unroll
    for (int kk = 0; kk < 2; ++kk) {
      short8 af[4], bfr[4];
      int kchunk = kk * 4 + (lane >> 4);
      #pragma unroll
      for (int mr = 0; mr < 4; ++mr) {
        int row = wr * 64 + mr * 16 + (lane & 15);
        af[mr] = *(const short8*)((const char*)sA + row * 128 +
                                  ((kchunk * 16) ^ ((row & 7) << 4)));
      }
      #pragma unroll
      for (int nr = 0; nr < 4; ++nr) {
        int row = wc * 64 + nr * 16 + (lane & 15);
        bfr[nr] = *(const short8*)((const char*)sB + row * 128 +
                                   ((kchunk * 16) ^ ((row & 7) << 4)));
      }
      #pragma unroll
      for (int mr = 0; mr < 4; ++mr)
        #pragma unroll
        for (int nr = 0; nr < 4; ++nr)
          acc[mr][nr] = __builtin_amdgcn_mfma_f32_16x16x32_bf16(af[mr], bfr[nr],
                                                                acc[mr][nr], 0, 0, 0);
    }
    __syncthreads();
  }

  #pragma unroll
  for (int mr = 0; mr < 4; ++mr)
    #pragma unroll
    for (int nr = 0; nr < 4; ++nr) {
      int col = bn * 128 + wc * 64 + nr * 16 + (lane & 15);
      float bv = bias[col];
      #pragma unroll
      for (int reg = 0; reg < 4; ++reg) {
        int row = bm * 128 + wr * 64 + mr * 16 + (lane >> 4) * 4 + reg;
        Cout[(long)row * Nout + col] = enc_fp8(acc[mr][nr][reg] + bv);
      }
    }
}

// ---------------- GEMM body (bf16 A via gload_lds) for layer 2 ----------------
__device__ __forceinline__ void gemm_body_bf(const ushort* __restrict__ A,
                                             const ushort* __restrict__ B,
                                             const float* __restrict__ bias,
                                             ushort* __restrict__ Cout,
                                             int K, int Nout, int bm, int bn,
                                             ushort* sA, ushort* sB) {
  const int t = threadIdx.x;
  const int lane = t & 63;
  const int wave = t >> 6;
  const int wr = wave >> 1, wc = wave & 1;

  f32x4 acc[4][4];
  #pragma unroll
  for (int i = 0; i < 4; i++)
    #pragma unroll
    for (int j = 0; j < 4; j++) acc[i][j] = (f32x4)0.f;

  const long a_base = (long)bm * 128 * K;
  const long b_base = (long)bn * 128 * K;

  for (int kt = 0; kt < K; kt += 64) {
    #pragma unroll
    for (int it = 0; it < 4; ++it) {
      int c = it * 256 + t;
      int r = c >> 3, ccp = c & 7;
      int cc = ccp ^ (r & 7);
      gload_lds16(A + a_base + (long)r * K + kt + cc * 8,
                  (char*)sA + (it * 256 + wave * 64) * 16);
      gload_lds16(B + b_base + (long)r * K + kt + cc * 8,
                  (char*)sB + (it * 256 + wave * 64) * 16);
    }
    __syncthreads();
    #pragma unroll
    for (int kk = 0; kk < 2; ++kk) {
      short8 af[4], bfr[4];
      int kchunk = kk * 4 + (lane >> 4);
      #pragma unroll
      for (int mr = 0; mr < 4; ++mr) {
        int row = wr * 64 + mr * 16 + (lane & 15);
        af[mr] = *(const short8*)((const char*)sA + row * 128 +
                                  ((kchunk * 16) ^ ((row & 7) << 4)));
      }
      #pragma unroll
      for (int nr = 0; nr < 4; ++nr) {
        int row = wc * 64 + nr * 16 + (lane & 15);
        bfr[nr] = *(const short8*)((const char*)sB + row * 128 +
                                   ((kchunk * 16) ^ ((row & 7) << 4)));
      }
      #pragma unroll
      for (int mr = 0; mr < 4; ++mr)
        #pragma unroll
        for (int nr = 0; nr < 4; ++nr)
          acc[mr][nr] = __builtin_amdgcn_mfma_f32_16x16x32_bf16(af[mr], bfr[nr],
                                                                acc[mr][nr], 0, 0, 0);
    }
    __syncthreads();
  }

  #pragma unroll
  for (int mr = 0; mr < 4; ++mr)
    #pragma unroll
    for (int nr = 0; nr < 4; ++nr) {
      int col = bn * 128 + wc * 64 + nr * 16 + (lane & 15);
      float bv = bias[col];
      #pragma unroll
      for (int reg = 0; reg < 4; ++reg) {
        int row = bm * 128 + wr * 64 + mr * 16 + (lane >> 4) * 4 + reg;
        Cout[(long)row * Nout + col] = f2bf(acc[mr][nr][reg] + bv);
      }
    }
}

// ---------------- fused: GEMM layer1 interleaved 1:2 with hist, XCD-grouped ----------------
// gemm-role block b=3g lands on XCD (3g)%8 (round-robin heuristic). Work mapping puts
// the 4 bn-blocks of each bm consecutively on the SAME XCD so x rows are fetched once
// into that XCD's L2: k=g/8 (round), r=(3g)&7 (XCD) -> bm = r + 8*(k/4), bn = k%4.
__global__ __launch_bounds__(256) void k_gemm1_hist(const float* __restrict__ X,
                                                    const ushort* __restrict__ B,
                                                    const float* __restrict__ bias,
                                                    uint8_t* __restrict__ C,
                                                    const int* __restrict__ src,
                                                    int* __restrict__ deg,
                                                    int* __restrict__ rank) {
  __shared__ ushort sA[128 * 64];
  __shared__ ushort sB[128 * 64];
  int b = blockIdx.x;
  int g = b / 3, rem = b - g * 3;
  if (rem == 0) {
    int k = g >> 3;
    int r = (3 * g) & 7;
    int bm = r + 8 * (k >> 2);
    if (bm < G1_BM) gemm1_body(X, B, bias, C, bm, k & 3, sA, sB);
  } else {
    int e = (g * 2 + rem - 1) * 256 + threadIdx.x;
    if (e < N_EDGES) rank[e] = atomicAdd(&deg[src[e]], 1);
  }
}

// ---------------- GEMM layer2 (bf16 out) ----------------
__global__ __launch_bounds__(256) void k_gemm2(const ushort* __restrict__ A,
                                               const ushort* __restrict__ B,
                                               const float* __restrict__ bias,
                                               ushort* __restrict__ C) {
  __shared__ ushort sA[128 * 64];
  __shared__ ushort sB[128 * 64];
  gemm_body_bf(A, B, bias, C, NHID, NCLASS, blockIdx.x, 0, sA, sB);
}

// ---------------- SpMM layer 1 (+ReLU): fp8 gather -> bf16 out ----------------
// wave per node; 2 edges per wave-step (32 lanes x 16B each); 4-step unroll (8 edges in flight).
__global__ __launch_bounds__(256) void k_spmm1(const int* __restrict__ rpb,
                                               const int* __restrict__ rpe,
                                               const uint2* __restrict__ esw,
                                               const uint8_t* __restrict__ c1,
                                               ushort* __restrict__ h) {
  int node = blockIdx.x * 4 + (threadIdx.x >> 6);   // < MPAD
  int lane = threadIdx.x & 63;
  int half = lane >> 5;
  int col = (lane & 31) * 16;   // fp8 byte/feature offset within row
  float a[16];
  #pragma unroll
  for (int k = 0; k < 16; ++k) a[k] = 0.f;
  if (node < N_NODES) {
    int beg = rpb[node], end = rpe[node];
    for (int j = beg; j < end; j += 8) {
      #pragma unroll
      for (int s = 0; s < 4; ++s) {
        int ei = j + s * 2 + half;
        bool vld = ei < end;
        uint2 p = esw[vld ? ei : 0];
        int d = (int)p.x;
        float w = vld ? __uint_as_float(p.y) : 0.f;
        uint4 q = *(const uint4*)(c1 + (long)d * NHID + col);
        acc_fp8x4(a, q.x, w);      acc_fp8x4(a + 4, q.y, w);
        acc_fp8x4(a + 8, q.z, w);  acc_fp8x4(a + 12, q.w, w);
      }
    }
  }
  #pragma unroll
  for (int k = 0; k < 16; ++k) a[k] += __shfl_xor(a[k], 32, 64);
  if (half == 0) {
    short8 o0, o1;
    #pragma unroll
    for (int k = 0; k < 8; ++k) {
      o0[k] = (short)f2bf(a[k] > 0.f ? a[k] : 0.f);
      o1[k] = (short)f2bf(a[k + 8] > 0.f ? a[k + 8] : 0.f);
    }
    *(short8*)(h + (long)node * NHID + col) = o0;       // pad nodes write zeros
    *(short8*)(h + (long)node * NHID + col + 8) = o1;
  }
}

// ---------------- SpMM layer 2: bf16 gather -> f32 out ----------------
// wave per node; 2 edges per wave-step (32 lanes x 8B = 256B row); 4-step unroll.
__global__ __launch_bounds__(256) void k_spmm2(const int* __restrict__ rpb,
                                               const int* __restrict__ rpe,
                                               const uint2* __restrict__ esw,
                                               const ushort* __restrict__ c2,
                                               float* __restrict__ out) {
  int node = blockIdx.x * 4 + (threadIdx.x >> 6);
  int lane = threadIdx.x & 63;
  int half = lane >> 5;
  int col = (lane & 31) * 4;   // 4 classes per lane
  if (node >= N_NODES) return;
  float a[4] = {0.f, 0.f, 0.f, 0.f};
  int beg = rpb[node], end = rpe[node];
  for (int j = beg; j < end; j += 8) {
    #pragma unroll
    for (int s = 0; s < 4; ++s) {
      int ei = j + s * 2 + half;
      bool vld = ei < end;
      uint2 p = esw[vld ? ei : 0];
      int d = (int)p.x;
      float w = vld ? __uint_as_float(p.y) : 0.f;
      uint2 q = *(const uint2*)(c2 + (long)d * NCLASS + col);
      acc_bf16x2(a, q.x, w);
      acc_bf16x2(a + 2, q.y, w);
    }
  }
  #pragma unroll
  for (int k = 0; k < 4; ++k) a[k] += __shfl_xor(a[k], 32, 64);
  if (half == 0) {
    f32x4 st; st[0] = a[0]; st[1] = a[1]; st[2] = a[2]; st[3] = a[3];
    *(f32x4*)(out + (long)node * NCLASS + col) = st;
  }
}

extern "C" void kernel_launch(void* const* d_in, const int* in_sizes, int n_in,
                              void* d_out, int out_size, void* d_ws, size_t ws_size,
                              hipStream_t stream) {
  const float* x    = (const float*)d_in[0];
  const float* ew   = (const float*)d_in[1];
  const float* W1   = (const float*)d_in[2];
  const float* b1   = (const float*)d_in[3];
  const float* W2   = (const float*)d_in[4];
  const float* b2   = (const float*)d_in[5];
  const int*   esrc = (const int*)d_in[6];
  const int*   edst = (const int*)d_in[7];
  float* out = (float*)d_out;

  char* ws = (char*)d_ws;
  size_t off = 0;
  auto alloc = [&](size_t bytes) -> void* {
    void* p = ws + off;
    off = (off + bytes + 255) & ~(size_t)255;
    return p;
  };

  ushort*  hbuf = (ushort*)alloc((size_t)MPAD * 512 * 2);  // h bf16 (after spmm1)
  uint8_t* c1f8 = (uint8_t*)alloc((size_t)MPAD * 512);     // c1 fp8
  ushort*  c2bf = (ushort*)alloc((size_t)MPAD * 128 * 2);  // c2 bf16
  ushort*  w1b  = (ushort*)alloc((size_t)512 * 512 * 2);
  ushort*  w2b  = (ushort*)alloc((size_t)128 * 512 * 2);
  int*     deg  = (int*)alloc((size_t)N_NODES * 4);
  int*     rpb  = (int*)alloc((size_t)N_NODES * 4);
  int*     rpe  = (int*)alloc((size_t)N_NODES * 4);
  int*     rank = (int*)alloc((size_t)N_EDGES * 4);
  int*     cnt  = (int*)alloc(256);
  uint2*   esw  = (uint2*)alloc((size_t)N_EDGES * 8);

  hipMemsetAsync(deg, 0, (size_t)N_NODES * 4, stream);
  hipMemsetAsync(cnt, 0, 4, stream);

  // prep: convert W1/W2 to bf16 (tiny)
  k_prepw<<<CONVW1_BLOCKS + CONVW2_BLOCKS, 256, 0, stream>>>(W1, w1b, W2, w2b);

  // layer-1 linear (f32 A in-register cvt, fp8 out, XCD-grouped)  ||  hist(+rank)
  k_gemm1_hist<<<G1H_BLOCKS, 256, 0, stream>>>(x, w1b, b1, c1f8, esrc, deg, rank);

  k_alloc<<<(N_NODES + 255) / 256, 256, 0, stream>>>(deg, rpb, rpe, cnt);

  // CSR fill: atomic-free, packed records
  k_fill<<<FILL_BLOCKS, 256, 0, stream>>>(esrc, edst, ew, rpb, rank, esw);

  // spmm + relu -> h (bf16)
  k_spmm1<<<MPAD / 4, 256, 0, stream>>>(rpb, rpe, esw, c1f8, hbuf);

  // layer-2 linear (bf16 out)
  k_gemm2<<<G1_BM, 256, 0, stream>>>(hbuf, w2b, b2, c2bf);

  // spmm -> out (f32)
  k_spmm2<<<(N_NODES + 3) / 4, 256, 0, stream>>>(rpb, rpe, esw, c2bf, out);
}

// Round 18
// 214.362 us; speedup vs baseline: 2.4563x; 1.1097x over previous
//
#include <hip/hip_runtime.h>
#include <hip/hip_bf16.h>
#include <hip/hip_fp8.h>
#include <stdint.h>

#define N_NODES 50000
#define N_EDGES 800000
#define NFEAT 512
#define NHID 512
#define NCLASS 128
#define MPAD 50048   // 391 * 128

#define CONVW1_BLOCKS 128    // 512*512/8/256
#define CONVW2_BLOCKS 32     // 128*512/8/256
#define G1_BM 391
#define G1H_GROUPS 1568      // 8*196 (padded so each XCD gets 196 gemm blocks)
#define G1H_BLOCKS 4704      // 3*1568  ({gemm,hist,hist} interleave)
#define FILL_BLOCKS 3125

typedef short short8 __attribute__((ext_vector_type(8)));
typedef float f32x4 __attribute__((ext_vector_type(4)));
typedef float f32x2 __attribute__((ext_vector_type(2)));

// RNE f32->bf16 via native __bf16 (compiler emits v_cvt_pk_bf16_f32 for pairs)
__device__ __forceinline__ ushort f2bf(float f) {
  __bf16 b = (__bf16)f;
  return __builtin_bit_cast(unsigned short, b);
}
__device__ __forceinline__ float bf2f(ushort h) {
  union { uint32_t u; float f; } v; v.u = ((uint32_t)h) << 16;
  return v.f;
}

// ---- fp8 e4m3 (OCP) encode/decode ----
__device__ __forceinline__ uint8_t enc_fp8(float f) {
#if __has_builtin(__builtin_amdgcn_cvt_pk_fp8_f32)
  int r = __builtin_amdgcn_cvt_pk_fp8_f32(f, f, 0, false);
  return (uint8_t)(r & 0xff);
#else
  __hip_fp8_e4m3 t(f);
  return t.__x;
#endif
}
__device__ __forceinline__ float dec_fp8_byte(uint32_t b) {
  uint32_t e = (b >> 3) & 15u, m = b & 7u, s = (b & 0x80u) << 24;
  union { uint32_t u; float f; } n; n.u = s | ((e + 120u) << 23) | (m << 20);
  union { uint32_t u; float f; } d; d.f = (float)m * 0x1p-9f; d.u |= s;
  return e ? n.f : d.f;
}

// decode 4 fp8 bytes in dword v, accumulate into a[0..3] with weight w
__device__ __forceinline__ void acc_fp8x4(float* a, uint32_t v, float w) {
#if __has_builtin(__builtin_amdgcn_cvt_pk_f32_fp8)
  f32x2 lo = __builtin_amdgcn_cvt_pk_f32_fp8(v, false);
  f32x2 hi = __builtin_amdgcn_cvt_pk_f32_fp8(v, true);
  a[0] += w * lo[0]; a[1] += w * lo[1]; a[2] += w * hi[0]; a[3] += w * hi[1];
#else
  a[0] += w * dec_fp8_byte(v & 0xffu);
  a[1] += w * dec_fp8_byte((v >> 8) & 0xffu);
  a[2] += w * dec_fp8_byte((v >> 16) & 0xffu);
  a[3] += w * dec_fp8_byte(v >> 24);
#endif
}

// decode 2 bf16 in dword v, accumulate into a[0..1] with weight w
__device__ __forceinline__ void acc_bf16x2(float* a, uint32_t v, float w) {
  a[0] += w * bf2f((ushort)(v & 0xffffu));
  a[1] += w * bf2f((ushort)(v >> 16));
}

__device__ __forceinline__ void conv8(const float* __restrict__ in,
                                      ushort* __restrict__ out, long idx) {
  const float4* p = (const float4*)(in + idx);
  float4 a = p[0], b = p[1];
  short8 o;
  o[0] = f2bf(a.x); o[1] = f2bf(a.y); o[2] = f2bf(a.z); o[3] = f2bf(a.w);
  o[4] = f2bf(b.x); o[5] = f2bf(b.y); o[6] = f2bf(b.z); o[7] = f2bf(b.w);
  *(short8*)(out + idx) = o;
}

// async global->LDS, 16B per lane; lds base must be wave-uniform
__device__ __forceinline__ void gload_lds16(const void* g, void* lds) {
  __builtin_amdgcn_global_load_lds(
      (const __attribute__((address_space(1))) void*)g,
      (__attribute__((address_space(3))) void*)lds,
      16, 0, 0);
}

// ---------------- prep: W1/W2 bf16 conversion only (tiny) ----------------
__global__ __launch_bounds__(256) void k_prepw(const float* __restrict__ W1,
                                               ushort* __restrict__ w1b,
                                               const float* __restrict__ W2,
                                               ushort* __restrict__ w2b) {
  int b = blockIdx.x, t = threadIdx.x;
  if (b < CONVW1_BLOCKS) {
    long idx = ((long)b * 256 + t) * 8;
    conv8(W1, w1b, idx);
  } else {
    long idx = ((long)(b - CONVW1_BLOCKS) * 256 + t) * 8;
    conv8(W2, w2b, idx);
  }
}

// ---------------- CSR segment allocation (unordered segments) ----------------
__global__ __launch_bounds__(256) void k_alloc(const int* __restrict__ deg,
                                               int* __restrict__ rpb,
                                               int* __restrict__ rpe,
                                               int* __restrict__ counter) {
  int i = blockIdx.x * blockDim.x + threadIdx.x;
  int lane = threadIdx.x & 63;
  int d = (i < N_NODES) ? deg[i] : 0;
  int sc = d;
  #pragma unroll
  for (int off = 1; off < 64; off <<= 1) {
    int u = __shfl_up(sc, off, 64);
    if (lane >= off) sc += u;
  }
  int base = 0;
  if (lane == 63) base = atomicAdd(counter, sc);
  base = __shfl(base, 63, 64);
  if (i < N_NODES) {
    int start = base + sc - d;
    rpb[i] = start;
    rpe[i] = start + d;
  }
}

// ---------------- CSR fill: atomic-free, packed 8B records ----------------
__global__ __launch_bounds__(256) void k_fill(const int* __restrict__ src,
                                              const int* __restrict__ dst,
                                              const float* __restrict__ w,
                                              const int* __restrict__ rpb,
                                              const int* __restrict__ rank,
                                              uint2* __restrict__ esw) {
  int e = blockIdx.x * blockDim.x + threadIdx.x;
  if (e < N_EDGES) {
    int pos = rpb[src[e]] + rank[e];
    uint2 p;
    p.x = (unsigned)dst[e];
    p.y = __float_as_uint(w[e]);
    esw[pos] = p;
  }
}

// ---------------- GEMM1 body: C_fp8 = bf16(x_f32) @ w1b^T + b1 ----------------
// A: reg-staged from f32 x; next-K prefetch into regs issued before MFMA phase
//    (T14 issue-early/write-late: HBM latency drains at end-of-MFMA barrier).
//    cvt via v_cvt_pk_bf16_f32 (native __bf16 cast); swizzled ds_write.
// B: global_load_lds width=16, linear LDS dest, inverse-swizzled global source.
__device__ __forceinline__ void gemm1_body(const float* __restrict__ X,
                                           const ushort* __restrict__ B,
                                           const float* __restrict__ bias,
                                           uint8_t* __restrict__ Cout,
                                           int bm, int bn,
                                           ushort* sA, ushort* sB) {
  const int K = NFEAT, Nout = NHID;
  const int t = threadIdx.x;
  const int lane = t & 63;
  const int wave = t >> 6;
  const int wr = wave >> 1, wc = wave & 1;

  f32x4 acc[4][4];
  #pragma unroll
  for (int i = 0; i < 4; i++)
    #pragma unroll
    for (int j = 0; j < 4; j++) acc[i][j] = (f32x4)0.f;

  const long b_base = (long)bn * 128 * K;

  float4 pa0[4], pa1[4];   // prefetched A (f32) for current kt
  #pragma unroll
  for (int it = 0; it < 4; ++it) {
    int c = it * 256 + t;
    int r = c >> 3, cc = c & 7;
    long grow = (long)bm * 128 + r;
    const float4* p = (const float4*)(X + (grow < N_NODES ? grow : 0) * (long)NFEAT + cc * 8);
    pa0[it] = p[0]; pa1[it] = p[1];
  }

  for (int kt = 0; kt < K; kt += 64) {
    // B staging: async to LDS
    #pragma unroll
    for (int it = 0; it < 4; ++it) {
      int c = it * 256 + t;
      int r = c >> 3, cc = c & 7;
      int ccg = cc ^ (r & 7);
      gload_lds16(B + b_base + (long)r * K + kt + ccg * 8,
                  (char*)sB + (it * 256 + wave * 64) * 16);
    }
    // A staging: cvt prefetched regs -> swizzled LDS
    #pragma unroll
    for (int it = 0; it < 4; ++it) {
      int c = it * 256 + t;
      int r = c >> 3, cc = c & 7;
      long grow = (long)bm * 128 + r;
      short8 o = (short8)0;
      if (grow < N_NODES) {
        o[0] = f2bf(pa0[it].x); o[1] = f2bf(pa0[it].y);
        o[2] = f2bf(pa0[it].z); o[3] = f2bf(pa0[it].w);
        o[4] = f2bf(pa1[it].x); o[5] = f2bf(pa1[it].y);
        o[6] = f2bf(pa1[it].z); o[7] = f2bf(pa1[it].w);
      }
      *(short8*)((char*)sA + r * 128 + ((cc ^ (r & 7)) * 16)) = o;
    }
    __syncthreads();
    // prefetch next kt's A (drains at end-of-MFMA barrier, hidden under MFMA)
    if (kt + 64 < K) {
      #pragma unroll
      for (int it = 0; it < 4; ++it) {
        int c = it * 256 + t;
        int r = c >> 3, cc = c & 7;
        long grow = (long)bm * 128 + r;
        const float4* p = (const float4*)(X + (grow < N_NODES ? grow : 0) * (long)NFEAT +
                                          (kt + 64) + cc * 8);
        pa0[it] = p[0]; pa1[it] = p[1];
      }
    }
    #pragma unroll
    for (int kk = 0; kk < 2; ++kk) {
      short8 af[4], bfr[4];
      int kchunk = kk * 4 + (lane >> 4);
      #pragma unroll
      for (int mr = 0; mr < 4; ++mr) {
        int row = wr * 64 + mr * 16 + (lane & 15);
        af[mr] = *(const short8*)((const char*)sA + row * 128 +
                                  ((kchunk * 16) ^ ((row & 7) << 4)));
      }
      #pragma unroll
      for (int nr = 0; nr < 4; ++nr) {
        int row = wc * 64 + nr * 16 + (lane & 15);
        bfr[nr] = *(const short8*)((const char*)sB + row * 128 +
                                   ((kchunk * 16) ^ ((row & 7) << 4)));
      }
      #pragma unroll
      for (int mr = 0; mr < 4; ++mr)
        #pragma unroll
        for (int nr = 0; nr < 4; ++nr)
          acc[mr][nr] = __builtin_amdgcn_mfma_f32_16x16x32_bf16(af[mr], bfr[nr],
                                                                acc[mr][nr], 0, 0, 0);
    }
    __syncthreads();
  }

  #pragma unroll
  for (int mr = 0; mr < 4; ++mr)
    #pragma unroll
    for (int nr = 0; nr < 4; ++nr) {
      int col = bn * 128 + wc * 64 + nr * 16 + (lane & 15);
      float bv = bias[col];
      #pragma unroll
      for (int reg = 0; reg < 4; ++reg) {
        int row = bm * 128 + wr * 64 + mr * 16 + (lane >> 4) * 4 + reg;
        Cout[(long)row * Nout + col] = enc_fp8(acc[mr][nr][reg] + bv);
      }
    }
}

// ---------------- GEMM body (bf16 A via gload_lds) for layer 2 ----------------
__device__ __forceinline__ void gemm_body_bf(const ushort* __restrict__ A,
                                             const ushort* __restrict__ B,
                                             const float* __restrict__ bias,
                                             ushort* __restrict__ Cout,
                                             int K, int Nout, int bm, int bn,
                                             ushort* sA, ushort* sB) {
  const int t = threadIdx.x;
  const int lane = t & 63;
  const int wave = t >> 6;
  const int wr = wave >> 1, wc = wave & 1;

  f32x4 acc[4][4];
  #pragma unroll
  for (int i = 0; i < 4; i++)
    #pragma unroll
    for (int j = 0; j < 4; j++) acc[i][j] = (f32x4)0.f;

  const long a_base = (long)bm * 128 * K;
  const long b_base = (long)bn * 128 * K;

  for (int kt = 0; kt < K; kt += 64) {
    #pragma unroll
    for (int it = 0; it < 4; ++it) {
      int c = it * 256 + t;
      int r = c >> 3, ccp = c & 7;
      int cc = ccp ^ (r & 7);
      gload_lds16(A + a_base + (long)r * K + kt + cc * 8,
                  (char*)sA + (it * 256 + wave * 64) * 16);
      gload_lds16(B + b_base + (long)r * K + kt + cc * 8,
                  (char*)sB + (it * 256 + wave * 64) * 16);
    }
    __syncthreads();
    #pragma unroll
    for (int kk = 0; kk < 2; ++kk) {
      short8 af[4], bfr[4];
      int kchunk = kk * 4 + (lane >> 4);
      #pragma unroll
      for (int mr = 0; mr < 4; ++mr) {
        int row = wr * 64 + mr * 16 + (lane & 15);
        af[mr] = *(const short8*)((const char*)sA + row * 128 +
                                  ((kchunk * 16) ^ ((row & 7) << 4)));
      }
      #pragma unroll
      for (int nr = 0; nr < 4; ++nr) {
        int row = wc * 64 + nr * 16 + (lane & 15);
        bfr[nr] = *(const short8*)((const char*)sB + row * 128 +
                                   ((kchunk * 16) ^ ((row & 7) << 4)));
      }
      #pragma unroll
      for (int mr = 0; mr < 4; ++mr)
        #pragma unroll
        for (int nr = 0; nr < 4; ++nr)
          acc[mr][nr] = __builtin_amdgcn_mfma_f32_16x16x32_bf16(af[mr], bfr[nr],
                                                                acc[mr][nr], 0, 0, 0);
    }
    __syncthreads();
  }

  #pragma unroll
  for (int mr = 0; mr < 4; ++mr)
    #pragma unroll
    for (int nr = 0; nr < 4; ++nr) {
      int col = bn * 128 + wc * 64 + nr * 16 + (lane & 15);
      float bv = bias[col];
      #pragma unroll
      for (int reg = 0; reg < 4; ++reg) {
        int row = bm * 128 + wr * 64 + mr * 16 + (lane >> 4) * 4 + reg;
        Cout[(long)row * Nout + col] = f2bf(acc[mr][nr][reg] + bv);
      }
    }
}

// ---------------- fused: GEMM layer1 interleaved 1:2 with hist, XCD-grouped ----------------
// gemm-role block b=3g lands on XCD (3g)%8 (round-robin heuristic). Work mapping puts
// the 4 bn-blocks of each bm consecutively on the SAME XCD so x rows are fetched once
// into that XCD's L2: k=g/8 (round), r=(3g)&7 (XCD) -> bm = r + 8*(k/4), bn = k%4.
__global__ __launch_bounds__(256) void k_gemm1_hist(const float* __restrict__ X,
                                                    const ushort* __restrict__ B,
                                                    const float* __restrict__ bias,
                                                    uint8_t* __restrict__ C,
                                                    const int* __restrict__ src,
                                                    int* __restrict__ deg,
                                                    int* __restrict__ rank) {
  __shared__ ushort sA[128 * 64];
  __shared__ ushort sB[128 * 64];
  int b = blockIdx.x;
  int g = b / 3, rem = b - g * 3;
  if (rem == 0) {
    int k = g >> 3;
    int r = (3 * g) & 7;
    int bm = r + 8 * (k >> 2);
    if (bm < G1_BM) gemm1_body(X, B, bias, C, bm, k & 3, sA, sB);
  } else {
    int e = (g * 2 + rem - 1) * 256 + threadIdx.x;
    if (e < N_EDGES) rank[e] = atomicAdd(&deg[src[e]], 1);
  }
}

// ---------------- GEMM layer2 (bf16 out) ----------------
__global__ __launch_bounds__(256) void k_gemm2(const ushort* __restrict__ A,
                                               const ushort* __restrict__ B,
                                               const float* __restrict__ bias,
                                               ushort* __restrict__ C) {
  __shared__ ushort sA[128 * 64];
  __shared__ ushort sB[128 * 64];
  gemm_body_bf(A, B, bias, C, NHID, NCLASS, blockIdx.x, 0, sA, sB);
}

// ---------------- SpMM layer 1 (+ReLU): fp8 gather -> bf16 out ----------------
// wave per node; 2 edges per wave-step (32 lanes x 16B each); 4-step unroll (8 edges in flight).
__global__ __launch_bounds__(256) void k_spmm1(const int* __restrict__ rpb,
                                               const int* __restrict__ rpe,
                                               const uint2* __restrict__ esw,
                                               const uint8_t* __restrict__ c1,
                                               ushort* __restrict__ h) {
  int node = blockIdx.x * 4 + (threadIdx.x >> 6);   // < MPAD
  int lane = threadIdx.x & 63;
  int half = lane >> 5;
  int col = (lane & 31) * 16;   // fp8 byte/feature offset within row
  float a[16];
  #pragma unroll
  for (int k = 0; k < 16; ++k) a[k] = 0.f;
  if (node < N_NODES) {
    int beg = rpb[node], end = rpe[node];
    for (int j = beg; j < end; j += 8) {
      #pragma unroll
      for (int s = 0; s < 4; ++s) {
        int ei = j + s * 2 + half;
        bool vld = ei < end;
        uint2 p = esw[vld ? ei : 0];
        int d = (int)p.x;
        float w = vld ? __uint_as_float(p.y) : 0.f;
        uint4 q = *(const uint4*)(c1 + (long)d * NHID + col);
        acc_fp8x4(a, q.x, w);      acc_fp8x4(a + 4, q.y, w);
        acc_fp8x4(a + 8, q.z, w);  acc_fp8x4(a + 12, q.w, w);
      }
    }
  }
  #pragma unroll
  for (int k = 0; k < 16; ++k) a[k] += __shfl_xor(a[k], 32, 64);
  if (half == 0) {
    short8 o0, o1;
    #pragma unroll
    for (int k = 0; k < 8; ++k) {
      o0[k] = (short)f2bf(a[k] > 0.f ? a[k] : 0.f);
      o1[k] = (short)f2bf(a[k + 8] > 0.f ? a[k + 8] : 0.f);
    }
    *(short8*)(h + (long)node * NHID + col) = o0;       // pad nodes write zeros
    *(short8*)(h + (long)node * NHID + col + 8) = o1;
  }
}

// ---------------- SpMM layer 2: bf16 gather -> f32 out ----------------
// wave per node; 2 edges per wave-step (32 lanes x 8B = 256B row); 4-step unroll.
__global__ __launch_bounds__(256) void k_spmm2(const int* __restrict__ rpb,
                                               const int* __restrict__ rpe,
                                               const uint2* __restrict__ esw,
                                               const ushort* __restrict__ c2,
                                               float* __restrict__ out) {
  int node = blockIdx.x * 4 + (threadIdx.x >> 6);
  int lane = threadIdx.x & 63;
  int half = lane >> 5;
  int col = (lane & 31) * 4;   // 4 classes per lane
  if (node >= N_NODES) return;
  float a[4] = {0.f, 0.f, 0.f, 0.f};
  int beg = rpb[node], end = rpe[node];
  for (int j = beg; j < end; j += 8) {
    #pragma unroll
    for (int s = 0; s < 4; ++s) {
      int ei = j + s * 2 + half;
      bool vld = ei < end;
      uint2 p = esw[vld ? ei : 0];
      int d = (int)p.x;
      float w = vld ? __uint_as_float(p.y) : 0.f;
      uint2 q = *(const uint2*)(c2 + (long)d * NCLASS + col);
      acc_bf16x2(a, q.x, w);
      acc_bf16x2(a + 2, q.y, w);
    }
  }
  #pragma unroll
  for (int k = 0; k < 4; ++k) a[k] += __shfl_xor(a[k], 32, 64);
  if (half == 0) {
    f32x4 st; st[0] = a[0]; st[1] = a[1]; st[2] = a[2]; st[3] = a[3];
    *(f32x4*)(out + (long)node * NCLASS + col) = st;
  }
}

extern "C" void kernel_launch(void* const* d_in, const int* in_sizes, int n_in,
                              void* d_out, int out_size, void* d_ws, size_t ws_size,
                              hipStream_t stream) {
  const float* x    = (const float*)d_in[0];
  const float* ew   = (const float*)d_in[1];
  const float* W1   = (const float*)d_in[2];
  const float* b1   = (const float*)d_in[3];
  const float* W2   = (const float*)d_in[4];
  const float* b2   = (const float*)d_in[5];
  const int*   esrc = (const int*)d_in[6];
  const int*   edst = (const int*)d_in[7];
  float* out = (float*)d_out;

  char* ws = (char*)d_ws;
  size_t off = 0;
  auto alloc = [&](size_t bytes) -> void* {
    void* p = ws + off;
    off = (off + bytes + 255) & ~(size_t)255;
    return p;
  };

  ushort*  hbuf = (ushort*)alloc((size_t)MPAD * 512 * 2);  // h bf16 (after spmm1)
  uint8_t* c1f8 = (uint8_t*)alloc((size_t)MPAD * 512);     // c1 fp8
  ushort*  c2bf = (ushort*)alloc((size_t)MPAD * 128 * 2);  // c2 bf16
  ushort*  w1b  = (ushort*)alloc((size_t)512 * 512 * 2);
  ushort*  w2b  = (ushort*)alloc((size_t)128 * 512 * 2);
  int*     deg  = (int*)alloc((size_t)N_NODES * 4);
  int*     rpb  = (int*)alloc((size_t)N_NODES * 4);
  int*     rpe  = (int*)alloc((size_t)N_NODES * 4);
  int*     rank = (int*)alloc((size_t)N_EDGES * 4);
  int*     cnt  = (int*)alloc(256);
  uint2*   esw  = (uint2*)alloc((size_t)N_EDGES * 8);

  hipMemsetAsync(deg, 0, (size_t)N_NODES * 4, stream);
  hipMemsetAsync(cnt, 0, 4, stream);

  // prep: convert W1/W2 to bf16 (tiny)
  k_prepw<<<CONVW1_BLOCKS + CONVW2_BLOCKS, 256, 0, stream>>>(W1, w1b, W2, w2b);

  // layer-1 linear (f32 A, cvt_pk + reg-prefetch, fp8 out, XCD-grouped)  ||  hist(+rank)
  k_gemm1_hist<<<G1H_BLOCKS, 256, 0, stream>>>(x, w1b, b1, c1f8, esrc, deg, rank);

  k_alloc<<<(N_NODES + 255) / 256, 256, 0, stream>>>(deg, rpb, rpe, cnt);

  // CSR fill: atomic-free, packed records
  k_fill<<<FILL_BLOCKS, 256, 0, stream>>>(esrc, edst, ew, rpb, rank, esw);

  // spmm + relu -> h (bf16)
  k_spmm1<<<MPAD / 4, 256, 0, stream>>>(rpb, rpe, esw, c1f8, hbuf);

  // layer-2 linear (bf16 out)
  k_gemm2<<<G1_BM, 256, 0, stream>>>(hbuf, w2b, b2, c2bf);

  // spmm -> out (f32)
  k_spmm2<<<(N_NODES + 3) / 4, 256, 0, stream>>>(rpb, rpe, esw, c2bf, out);
}